// Round 1
// baseline (1368.993 us; speedup 1.0000x reference)
//
#include <hip/hip_runtime.h>
#include <hip/hip_bf16.h>

#define N_NODES 50000
#define N_EDGES 1600000
#define E_TOT   1650000   // edges + self loops
#define F_IN    128
#define HID     32
#define HEADS   3
#define C1      96        // HEADS*HID
#define OUT_F   16
#define NEG_SLOPE 0.2f

// ---- float atomic-max encoding (order-preserving unsigned) ----
__device__ __forceinline__ unsigned fenc(float f) {
    unsigned u = __float_as_uint(f);
    return (u & 0x80000000u) ? ~u : (u | 0x80000000u);
}
__device__ __forceinline__ float fdec(unsigned u) {
    return __uint_as_float((u & 0x80000000u) ? (u & 0x7fffffffu) : ~u);
}
__device__ __forceinline__ float lrelu(float v) {
    return v > 0.f ? v : NEG_SLOPE * v;
}
__device__ __forceinline__ void edge_sd(int e, const int* __restrict__ src,
                                        const int* __restrict__ dst, int& s, int& d) {
    if (e < N_EDGES) { s = src[e]; d = dst[e]; }
    else { s = d = e - N_EDGES; }
}

// ---------- Layer 1: h1 = x @ W1 (one block of 128 per node), plus att dots ----------
__global__ void l1_gemm(const float* __restrict__ x, const float* __restrict__ W1,
                        const float* __restrict__ attS, const float* __restrict__ attD,
                        float* __restrict__ h1, float* __restrict__ aS1, float* __restrict__ aD1) {
    int n = blockIdx.x;
    int t = threadIdx.x;           // 128 threads
    __shared__ float xs[F_IN];
    __shared__ float ps[C1], pd[C1];
    xs[t] = x[n * F_IN + t];
    __syncthreads();
    if (t < C1) {
        float acc = 0.f;
#pragma unroll 8
        for (int k = 0; k < F_IN; ++k) acc = fmaf(xs[k], W1[k * C1 + t], acc);
        h1[n * C1 + t] = acc;
        ps[t] = acc * attS[t];
        pd[t] = acc * attD[t];
    }
    __syncthreads();
    if (t < HEADS) {
        float s = 0.f, d = 0.f;
#pragma unroll
        for (int f = 0; f < HID; ++f) { s += ps[t * HID + f]; d += pd[t * HID + f]; }
        aS1[n * HEADS + t] = s;
        aD1[n * HEADS + t] = d;
    }
}

// ---------- Layer 1 edge passes ----------
__global__ void l1_edge_max(const int* __restrict__ src, const int* __restrict__ dst,
                            const float* __restrict__ aS1, const float* __restrict__ aD1,
                            unsigned* __restrict__ mx) {
    int e = blockIdx.x * blockDim.x + threadIdx.x;
    if (e >= E_TOT) return;
    int s, d; edge_sd(e, src, dst, s, d);
#pragma unroll
    for (int h = 0; h < HEADS; ++h) {
        float v = lrelu(aS1[s * HEADS + h] + aD1[d * HEADS + h]);
        atomicMax(&mx[d * HEADS + h], fenc(v));
    }
}

__global__ void l1_edge_sum(const int* __restrict__ src, const int* __restrict__ dst,
                            const float* __restrict__ aS1, const float* __restrict__ aD1,
                            const unsigned* __restrict__ mx, float* __restrict__ p1,
                            float* __restrict__ den) {
    int e = blockIdx.x * blockDim.x + threadIdx.x;
    if (e >= E_TOT) return;
    int s, d; edge_sd(e, src, dst, s, d);
#pragma unroll
    for (int h = 0; h < HEADS; ++h) {
        float v = lrelu(aS1[s * HEADS + h] + aD1[d * HEADS + h]);
        float p = expf(v - fdec(mx[d * HEADS + h]));
        p1[e * HEADS + h] = p;
        atomicAdd(&den[d * HEADS + h], p);
    }
}

__global__ void l1_aggr(const int* __restrict__ src, const int* __restrict__ dst,
                        const float* __restrict__ h1, const float* __restrict__ p1,
                        const float* __restrict__ den, float* __restrict__ acc) {
    int gid = blockIdx.x * blockDim.x + threadIdx.x;
    if (gid >= E_TOT * C1) return;
    int e = gid / C1, f = gid % C1;
    int s, d; edge_sd(e, src, dst, s, d);
    int h = f >> 5;
    float alpha = p1[e * HEADS + h] / den[d * HEADS + h];
    atomicAdd(&acc[d * C1 + f], h1[s * C1 + f] * alpha);
}

__global__ void l1_relu_bias(float* __restrict__ acc, const float* __restrict__ bias) {
    int i = blockIdx.x * blockDim.x + threadIdx.x;
    if (i >= N_NODES * C1) return;
    float v = acc[i] + bias[i % C1];
    acc[i] = v > 0.f ? v : 0.f;
}

// ---------- Layer 2 ----------
__global__ void l2_gemm(const float* __restrict__ h, const float* __restrict__ W2,
                        float* __restrict__ h2) {
    int gid = blockIdx.x * blockDim.x + threadIdx.x;
    if (gid >= N_NODES * OUT_F) return;
    int n = gid / OUT_F, o = gid % OUT_F;
    float acc = 0.f;
#pragma unroll 8
    for (int k = 0; k < C1; ++k) acc = fmaf(h[n * C1 + k], W2[k * OUT_F + o], acc);
    h2[gid] = acc;
}

__global__ void l2_att(const float* __restrict__ h2, const float* __restrict__ attS,
                       const float* __restrict__ attD, float* __restrict__ aS2,
                       float* __restrict__ aD2) {
    int n = blockIdx.x * blockDim.x + threadIdx.x;
    if (n >= N_NODES) return;
    float s = 0.f, d = 0.f;
#pragma unroll
    for (int o = 0; o < OUT_F; ++o) {
        float v = h2[n * OUT_F + o];
        s += v * attS[o];
        d += v * attD[o];
    }
    aS2[n] = s; aD2[n] = d;
}

__global__ void l2_edge_max(const int* __restrict__ src, const int* __restrict__ dst,
                            const float* __restrict__ aS2, const float* __restrict__ aD2,
                            unsigned* __restrict__ mx) {
    int e = blockIdx.x * blockDim.x + threadIdx.x;
    if (e >= E_TOT) return;
    int s, d; edge_sd(e, src, dst, s, d);
    atomicMax(&mx[d], fenc(lrelu(aS2[s] + aD2[d])));
}

__global__ void l2_edge_sum(const int* __restrict__ src, const int* __restrict__ dst,
                            const float* __restrict__ aS2, const float* __restrict__ aD2,
                            const unsigned* __restrict__ mx, float* __restrict__ p2,
                            float* __restrict__ den) {
    int e = blockIdx.x * blockDim.x + threadIdx.x;
    if (e >= E_TOT) return;
    int s, d; edge_sd(e, src, dst, s, d);
    float p = expf(lrelu(aS2[s] + aD2[d]) - fdec(mx[d]));
    p2[e] = p;
    atomicAdd(&den[d], p);
}

__global__ void l2_aggr(const int* __restrict__ src, const int* __restrict__ dst,
                        const float* __restrict__ h2, const float* __restrict__ p2,
                        const float* __restrict__ den, float* __restrict__ acc) {
    int gid = blockIdx.x * blockDim.x + threadIdx.x;
    if (gid >= E_TOT * OUT_F) return;
    int e = gid / OUT_F, o = gid % OUT_F;
    int s, d; edge_sd(e, src, dst, s, d);
    float alpha = p2[e] / den[d];
    atomicAdd(&acc[d * OUT_F + o], h2[s * OUT_F + o] * alpha);
}

// ---------- final: + bias2, log_softmax over 16 ----------
__global__ void final_lsm(const float* __restrict__ acc, const float* __restrict__ bias,
                          float* __restrict__ out) {
    int n = blockIdx.x * blockDim.x + threadIdx.x;
    if (n >= N_NODES) return;
    float v[OUT_F];
    float mx = -3.4e38f;
#pragma unroll
    for (int o = 0; o < OUT_F; ++o) {
        v[o] = acc[n * OUT_F + o] + bias[o];
        mx = fmaxf(mx, v[o]);
    }
    float sum = 0.f;
#pragma unroll
    for (int o = 0; o < OUT_F; ++o) sum += expf(v[o] - mx);
    float lse = mx + logf(sum);
#pragma unroll
    for (int o = 0; o < OUT_F; ++o) out[n * OUT_F + o] = v[o] - lse;
}

extern "C" void kernel_launch(void* const* d_in, const int* in_sizes, int n_in,
                              void* d_out, int out_size, void* d_ws, size_t ws_size,
                              hipStream_t stream) {
    const float* x      = (const float*)d_in[0];
    const int*   ei     = (const int*)  d_in[1];
    const float* W1     = (const float*)d_in[2];
    const float* attS1  = (const float*)d_in[3];
    const float* attD1  = (const float*)d_in[4];
    const float* bias1  = (const float*)d_in[5];
    const float* W2     = (const float*)d_in[6];
    const float* attS2  = (const float*)d_in[7];
    const float* attD2  = (const float*)d_in[8];
    const float* bias2  = (const float*)d_in[9];
    const int* src = ei;
    const int* dst = ei + N_EDGES;
    float* out = (float*)d_out;

    // ---- workspace layout (floats) ----
    float* ws = (float*)d_ws;
    size_t off = 0;
    // zero-region (memset each call): mx1, den1, acc1, mx2, den2, acc2
    unsigned* mx1  = (unsigned*)(ws + off); off += (size_t)N_NODES * HEADS;
    float*    den1 = ws + off;              off += (size_t)N_NODES * HEADS;
    float*    acc1 = ws + off;              off += (size_t)N_NODES * C1;
    unsigned* mx2  = (unsigned*)(ws + off); off += N_NODES;
    float*    den2 = ws + off;              off += N_NODES;
    float*    acc2 = ws + off;              off += (size_t)N_NODES * OUT_F;
    size_t zero_floats = off;
    float*    h1   = ws + off;              off += (size_t)N_NODES * C1;
    float*    aS1  = ws + off;              off += (size_t)N_NODES * HEADS;
    float*    aD1  = ws + off;              off += (size_t)N_NODES * HEADS;
    float*    p1   = ws + off;              off += (size_t)E_TOT * HEADS;
    float*    h2   = ws + off;              off += (size_t)N_NODES * OUT_F;
    float*    aS2  = ws + off;              off += N_NODES;
    float*    aD2  = ws + off;              off += N_NODES;
    float*    p2   = ws + off;              off += (size_t)E_TOT;
    (void)ws_size; (void)in_sizes; (void)n_in; (void)out_size;

    hipMemsetAsync(d_ws, 0, zero_floats * sizeof(float), stream);

    // ---- layer 1 ----
    l1_gemm<<<N_NODES, F_IN, 0, stream>>>(x, W1, attS1, attD1, h1, aS1, aD1);
    {
        int nb = (E_TOT + 255) / 256;
        l1_edge_max<<<nb, 256, 0, stream>>>(src, dst, aS1, aD1, mx1);
        l1_edge_sum<<<nb, 256, 0, stream>>>(src, dst, aS1, aD1, mx1, p1, den1);
    }
    {
        long long tot = (long long)E_TOT * C1;
        int nb = (int)((tot + 255) / 256);
        l1_aggr<<<nb, 256, 0, stream>>>(src, dst, h1, p1, den1, acc1);
    }
    {
        int nb = (N_NODES * C1 + 255) / 256;
        l1_relu_bias<<<nb, 256, 0, stream>>>(acc1, bias1);
    }

    // ---- layer 2 ----
    {
        int nb = (N_NODES * OUT_F + 255) / 256;
        l2_gemm<<<nb, 256, 0, stream>>>(acc1, W2, h2);
        int nb2 = (N_NODES + 255) / 256;
        l2_att<<<nb2, 256, 0, stream>>>(h2, attS2, attD2, aS2, aD2);
        int nbe = (E_TOT + 255) / 256;
        l2_edge_max<<<nbe, 256, 0, stream>>>(src, dst, aS2, aD2, mx2);
        l2_edge_sum<<<nbe, 256, 0, stream>>>(src, dst, aS2, aD2, mx2, p2, den2);
        long long tot = (long long)E_TOT * OUT_F;
        int nba = (int)((tot + 255) / 256);
        l2_aggr<<<nba, 256, 0, stream>>>(src, dst, h2, p2, den2, acc2);
    }

    // ---- final ----
    {
        int nb = (N_NODES + 255) / 256;
        final_lsm<<<nb, 256, 0, stream>>>(acc2, bias2, out);
    }
}

// Round 3
// 556.651 us; speedup vs baseline: 2.4593x; 2.4593x over previous
//
#include <hip/hip_runtime.h>
#include <hip/hip_bf16.h>

#define N_NODES 50000
#define N_EDGES 1600000
#define E_TOT   1650000   // edges + self loops
#define F_IN    128
#define HID     32
#define HEADS   3
#define C1      96        // HEADS*HID
#define OUT_F   16
#define NEG_SLOPE 0.2f
#define NB_SCAN 196       // ceil(50000/256)

__device__ __forceinline__ float lrelu(float v) {
    return v > 0.f ? v : NEG_SLOPE * v;
}
__device__ __forceinline__ void edge_sd(int e, const int* __restrict__ src,
                                        const int* __restrict__ dst, int& s, int& d) {
    if (e < N_EDGES) { s = src[e]; d = dst[e]; }
    else { s = d = e - N_EDGES; }
}
__device__ __forceinline__ float wave_max(float v) {
#pragma unroll
    for (int o = 32; o; o >>= 1) v = fmaxf(v, __shfl_xor(v, o));
    return v;
}
__device__ __forceinline__ float wave_sum(float v) {
#pragma unroll
    for (int o = 32; o; o >>= 1) v += __shfl_xor(v, o);
    return v;
}

// ================= CSR construction =================
__global__ void k_deg(const int* __restrict__ src, const int* __restrict__ dst,
                      int* __restrict__ deg) {
    int e = blockIdx.x * blockDim.x + threadIdx.x;
    if (e >= E_TOT) return;
    int s, d; edge_sd(e, src, dst, s, d);
    atomicAdd(&deg[d], 1);
}

__global__ void k_scan1(const int* __restrict__ deg, int* __restrict__ inc,
                        int* __restrict__ bsum) {
    __shared__ int sh[256];
    int t = threadIdx.x;
    int i = blockIdx.x * 256 + t;
    int v = (i < N_NODES) ? deg[i] : 0;
    sh[t] = v; __syncthreads();
#pragma unroll
    for (int o = 1; o < 256; o <<= 1) {
        int u = (t >= o) ? sh[t - o] : 0;
        __syncthreads();
        sh[t] += u;
        __syncthreads();
    }
    if (i < N_NODES) inc[i] = sh[t];
    if (t == 255) bsum[blockIdx.x] = sh[255];
}

__global__ void k_scan2(int* __restrict__ bsum) {
    __shared__ int sh[256];
    int t = threadIdx.x;
    int v = (t < NB_SCAN) ? bsum[t] : 0;
    sh[t] = v; __syncthreads();
#pragma unroll
    for (int o = 1; o < 256; o <<= 1) {
        int u = (t >= o) ? sh[t - o] : 0;
        __syncthreads();
        sh[t] += u;
        __syncthreads();
    }
    if (t < NB_SCAN) bsum[t] = sh[t];
}

__global__ void k_scan3(const int* __restrict__ inc, const int* __restrict__ bsum,
                        int* __restrict__ row) {
    int i = blockIdx.x * blockDim.x + threadIdx.x;
    if (i < N_NODES) {
        int add = blockIdx.x ? bsum[blockIdx.x - 1] : 0;
        row[i + 1] = inc[i] + add;
    }
    if (i == 0) row[0] = 0;
}

__global__ void k_scatter(const int* __restrict__ src, const int* __restrict__ dst,
                          const int* __restrict__ row, int* __restrict__ cursor,
                          int* __restrict__ csr_src) {
    int e = blockIdx.x * blockDim.x + threadIdx.x;
    if (e >= E_TOT) return;
    int s, d; edge_sd(e, src, dst, s, d);
    int slot = row[d] + atomicAdd(&cursor[d], 1);
    csr_src[slot] = s;
}

// ================= Layer 1 GEMM + attention dots =================
__global__ void l1_gemm(const float* __restrict__ x, const float* __restrict__ W1,
                        const float* __restrict__ attS, const float* __restrict__ attD,
                        float* __restrict__ h1, float* __restrict__ aS1, float* __restrict__ aD1) {
    int n = blockIdx.x;
    int t = threadIdx.x;           // 128 threads
    __shared__ float xs[F_IN];
    __shared__ float ps[C1], pd[C1];
    xs[t] = x[n * F_IN + t];
    __syncthreads();
    if (t < C1) {
        float acc = 0.f;
#pragma unroll 8
        for (int k = 0; k < F_IN; ++k) acc = fmaf(xs[k], W1[k * C1 + t], acc);
        h1[n * C1 + t] = acc;
        ps[t] = acc * attS[t];
        pd[t] = acc * attD[t];
    }
    __syncthreads();
    if (t < HEADS) {
        float s = 0.f, d = 0.f;
#pragma unroll
        for (int f = 0; f < HID; ++f) { s += ps[t * HID + f]; d += pd[t * HID + f]; }
        aS1[n * HEADS + t] = s;
        aD1[n * HEADS + t] = d;
    }
}

// ================= Layer 1 fused softmax + aggregate (1 wave / node) =================
__global__ __launch_bounds__(256) void l1_node(const int* __restrict__ row,
                                               const int* __restrict__ csr_src,
                                               const float* __restrict__ h1,
                                               const float* __restrict__ aS1,
                                               const float* __restrict__ aD1,
                                               const float* __restrict__ bias1,
                                               float* __restrict__ hout) {
    int n = (blockIdx.x * blockDim.x + threadIdx.x) >> 6;
    int lane = threadIdx.x & 63;
    if (n >= N_NODES) return;
    int rs = row[n], re = row[n + 1];
    float ad0 = aD1[n * 3 + 0], ad1 = aD1[n * 3 + 1], ad2 = aD1[n * 3 + 2];

    // P1: per-head max over neighborhood
    float m0 = -1e30f, m1 = -1e30f, m2 = -1e30f;
    for (int i = rs + lane; i < re; i += 64) {
        int s = csr_src[i];
        m0 = fmaxf(m0, lrelu(aS1[s * 3 + 0] + ad0));
        m1 = fmaxf(m1, lrelu(aS1[s * 3 + 1] + ad1));
        m2 = fmaxf(m2, lrelu(aS1[s * 3 + 2] + ad2));
    }
    m0 = wave_max(m0); m1 = wave_max(m1); m2 = wave_max(m2);

    // P2: denominators
    float s0 = 0.f, s1 = 0.f, s2 = 0.f;
    for (int i = rs + lane; i < re; i += 64) {
        int s = csr_src[i];
        s0 += expf(lrelu(aS1[s * 3 + 0] + ad0) - m0);
        s1 += expf(lrelu(aS1[s * 3 + 1] + ad1) - m1);
        s2 += expf(lrelu(aS1[s * 3 + 2] + ad2) - m2);
    }
    s0 = wave_sum(s0); s1 = wave_sum(s1); s2 = wave_sum(s2);
    float r0 = 1.f / s0, r1 = 1.f / s1, r2 = 1.f / s2;

    // P3: feature aggregation. lane owns feature `lane` (head lane>>5) and,
    // for lane<32, feature 64+lane (head 2).
    int   hA  = lane >> 5;
    float mA  = hA ? m1 : m0;
    float rA  = hA ? r1 : r0;
    float adA = hA ? ad1 : ad0;
    float accA = 0.f, accB = 0.f;
    for (int i = rs; i < re; ++i) {
        int s = csr_src[i];
        float aA = expf(lrelu(aS1[s * 3 + hA] + adA) - mA) * rA;
        accA = fmaf(h1[s * C1 + lane], aA, accA);
        if (lane < 32) {
            float aB = expf(lrelu(aS1[s * 3 + 2] + ad2) - m2) * r2;
            accB = fmaf(h1[s * C1 + 64 + lane], aB, accB);
        }
    }
    float v = accA + bias1[lane];
    hout[n * C1 + lane] = v > 0.f ? v : 0.f;
    if (lane < 32) {
        float v2 = accB + bias1[64 + lane];
        hout[n * C1 + 64 + lane] = v2 > 0.f ? v2 : 0.f;
    }
}

// ================= Layer 2 GEMM (96->16) + att dots =================
__global__ void l2_gemm(const float* __restrict__ h, const float* __restrict__ W2,
                        float* __restrict__ h2) {
    int gid = blockIdx.x * blockDim.x + threadIdx.x;
    if (gid >= N_NODES * OUT_F) return;
    int n = gid / OUT_F, o = gid % OUT_F;
    float acc = 0.f;
#pragma unroll 8
    for (int k = 0; k < C1; ++k) acc = fmaf(h[n * C1 + k], W2[k * OUT_F + o], acc);
    h2[gid] = acc;
}

__global__ void l2_att(const float* __restrict__ h2, const float* __restrict__ attS,
                       const float* __restrict__ attD, float* __restrict__ aS2,
                       float* __restrict__ aD2) {
    int n = blockIdx.x * blockDim.x + threadIdx.x;
    if (n >= N_NODES) return;
    float s = 0.f, d = 0.f;
#pragma unroll
    for (int o = 0; o < OUT_F; ++o) {
        float v = h2[n * OUT_F + o];
        s += v * attS[o];
        d += v * attD[o];
    }
    aS2[n] = s; aD2[n] = d;
}

// ========= Layer 2 fused softmax + aggregate + bias + log_softmax (1 wave / node) ====
__global__ __launch_bounds__(256) void l2_node(const int* __restrict__ row,
                                               const int* __restrict__ csr_src,
                                               const float* __restrict__ h2,
                                               const float* __restrict__ aS2,
                                               const float* __restrict__ aD2,
                                               const float* __restrict__ bias2,
                                               float* __restrict__ out) {
    int n = (blockIdx.x * blockDim.x + threadIdx.x) >> 6;
    int lane = threadIdx.x & 63;
    if (n >= N_NODES) return;
    int rs = row[n], re = row[n + 1];
    float adn = aD2[n];

    // P1: max
    float m = -1e30f;
    for (int i = rs + lane; i < re; i += 64)
        m = fmaxf(m, lrelu(aS2[csr_src[i]] + adn));
    m = wave_max(m);

    // P2: denom
    float sm = 0.f;
    for (int i = rs + lane; i < re; i += 64)
        sm += expf(lrelu(aS2[csr_src[i]] + adn) - m);
    sm = wave_sum(sm);
    float r = 1.f / sm;

    // P3: 4 edges in flight (16 lanes each)
    int g = lane >> 4, fl = lane & 15;
    float acc = 0.f;
    for (int i = rs + g; i < re; i += 4) {
        int s = csr_src[i];
        float a = expf(lrelu(aS2[s] + adn) - m) * r;
        acc = fmaf(h2[s * OUT_F + fl], a, acc);
    }
    acc += __shfl_xor(acc, 16);
    acc += __shfl_xor(acc, 32);

    // epilogue: bias + log_softmax over the 16 features (within each 16-lane group)
    float v = acc + bias2[fl];
    float mm = v;
#pragma unroll
    for (int o = 1; o < 16; o <<= 1) mm = fmaxf(mm, __shfl_xor(mm, o));
    float se = expf(v - mm);
#pragma unroll
    for (int o = 1; o < 16; o <<= 1) se += __shfl_xor(se, o);
    float lse = mm + logf(se);
    if (lane < 16) out[n * OUT_F + fl] = v - lse;
}

extern "C" void kernel_launch(void* const* d_in, const int* in_sizes, int n_in,
                              void* d_out, int out_size, void* d_ws, size_t ws_size,
                              hipStream_t stream) {
    const float* x      = (const float*)d_in[0];
    const int*   ei     = (const int*)  d_in[1];
    const float* W1     = (const float*)d_in[2];
    const float* attS1  = (const float*)d_in[3];
    const float* attD1  = (const float*)d_in[4];
    const float* bias1  = (const float*)d_in[5];
    const float* W2     = (const float*)d_in[6];
    const float* attS2  = (const float*)d_in[7];
    const float* attD2  = (const float*)d_in[8];
    const float* bias2  = (const float*)d_in[9];
    const int* src = ei;
    const int* dst = ei + N_EDGES;
    float* out = (float*)d_out;
    (void)in_sizes; (void)n_in; (void)out_size; (void)ws_size;

    // ---- workspace layout ----
    char* wsb = (char*)d_ws;
    size_t off = 0;
    // zero region: deg + cursor
    int* deg    = (int*)(wsb + off); off += (size_t)N_NODES * 4;
    int* cursor = (int*)(wsb + off); off += (size_t)N_NODES * 4;
    size_t zero_bytes = off;
    int* inc    = (int*)(wsb + off); off += (size_t)N_NODES * 4;
    int* bsum   = (int*)(wsb + off); off += 256 * 4;
    int* row    = (int*)(wsb + off); off += ((size_t)N_NODES + 1) * 4;
    int* csr    = (int*)(wsb + off); off += (size_t)E_TOT * 4;
    float* h1   = (float*)(wsb + off); off += (size_t)N_NODES * C1 * 4;
    float* aS1  = (float*)(wsb + off); off += (size_t)N_NODES * HEADS * 4;
    float* aD1  = (float*)(wsb + off); off += (size_t)N_NODES * HEADS * 4;
    float* hmid = (float*)(wsb + off); off += (size_t)N_NODES * C1 * 4;
    float* h2   = (float*)(wsb + off); off += (size_t)N_NODES * OUT_F * 4;
    float* aS2  = (float*)(wsb + off); off += (size_t)N_NODES * 4;
    float* aD2  = (float*)(wsb + off); off += (size_t)N_NODES * 4;

    hipMemsetAsync(d_ws, 0, zero_bytes, stream);

    int nbe = (E_TOT + 255) / 256;
    // CSR build
    k_deg<<<nbe, 256, 0, stream>>>(src, dst, deg);
    k_scan1<<<NB_SCAN, 256, 0, stream>>>(deg, inc, bsum);
    k_scan2<<<1, 256, 0, stream>>>(bsum);
    k_scan3<<<NB_SCAN, 256, 0, stream>>>(inc, bsum, row);
    k_scatter<<<nbe, 256, 0, stream>>>(src, dst, row, cursor, csr);

    // layer 1
    l1_gemm<<<N_NODES, F_IN, 0, stream>>>(x, W1, attS1, attD1, h1, aS1, aD1);
    {
        int waves_per_block = 4;                       // 256 threads
        int nb = (N_NODES + waves_per_block - 1) / waves_per_block;
        l1_node<<<nb, 256, 0, stream>>>(row, csr, h1, aS1, aD1, bias1, hmid);
    }

    // layer 2
    {
        int nb = (N_NODES * OUT_F + 255) / 256;
        l2_gemm<<<nb, 256, 0, stream>>>(hmid, W2, h2);
        int nb2 = (N_NODES + 255) / 256;
        l2_att<<<nb2, 256, 0, stream>>>(h2, attS2, attD2, aS2, aD2);
        int nbn = (N_NODES + 3) / 4;
        l2_node<<<nbn, 256, 0, stream>>>(row, csr, h2, aS2, aD2, bias2, out);
    }
}

// Round 4
// 525.957 us; speedup vs baseline: 2.6029x; 1.0584x over previous
//
#include <hip/hip_runtime.h>
#include <hip/hip_bf16.h>

#define N_NODES 50000
#define N_EDGES 1600000
#define E_TOT   1650000   // edges + self loops
#define F_IN    128
#define HID     32
#define HEADS   3
#define C1      96        // HEADS*HID
#define OUT_F   16
#define NEG_SLOPE 0.2f
#define NB_SCAN 196       // ceil(50000/256)

__device__ __forceinline__ float lrelu(float v) {
    return v > 0.f ? v : NEG_SLOPE * v;
}
__device__ __forceinline__ void edge_sd(int e, const int* __restrict__ src,
                                        const int* __restrict__ dst, int& s, int& d) {
    if (e < N_EDGES) { s = src[e]; d = dst[e]; }
    else { s = d = e - N_EDGES; }
}
__device__ __forceinline__ float wave_sum(float v) {
#pragma unroll
    for (int o = 32; o; o >>= 1) v += __shfl_xor(v, o);
    return v;
}

// ================= CSR construction =================
__global__ void k_deg(const int* __restrict__ src, const int* __restrict__ dst,
                      int* __restrict__ deg) {
    int e = blockIdx.x * blockDim.x + threadIdx.x;
    if (e >= E_TOT) return;
    int s, d; edge_sd(e, src, dst, s, d);
    atomicAdd(&deg[d], 1);
}

__global__ void k_scan1(const int* __restrict__ deg, int* __restrict__ inc,
                        int* __restrict__ bsum) {
    __shared__ int sh[256];
    int t = threadIdx.x;
    int i = blockIdx.x * 256 + t;
    int v = (i < N_NODES) ? deg[i] : 0;
    sh[t] = v; __syncthreads();
#pragma unroll
    for (int o = 1; o < 256; o <<= 1) {
        int u = (t >= o) ? sh[t - o] : 0;
        __syncthreads();
        sh[t] += u;
        __syncthreads();
    }
    if (i < N_NODES) inc[i] = sh[t];
    if (t == 255) bsum[blockIdx.x] = sh[255];
}

__global__ void k_scan2(int* __restrict__ bsum) {
    __shared__ int sh[256];
    int t = threadIdx.x;
    int v = (t < NB_SCAN) ? bsum[t] : 0;
    sh[t] = v; __syncthreads();
#pragma unroll
    for (int o = 1; o < 256; o <<= 1) {
        int u = (t >= o) ? sh[t - o] : 0;
        __syncthreads();
        sh[t] += u;
        __syncthreads();
    }
    if (t < NB_SCAN) bsum[t] = sh[t];
}

__global__ void k_scan3(const int* __restrict__ inc, const int* __restrict__ bsum,
                        int* __restrict__ row) {
    int i = blockIdx.x * blockDim.x + threadIdx.x;
    if (i < N_NODES) {
        int add = blockIdx.x ? bsum[blockIdx.x - 1] : 0;
        row[i + 1] = inc[i] + add;
    }
    if (i == 0) row[0] = 0;
}

__global__ void k_scatter(const int* __restrict__ src, const int* __restrict__ dst,
                          const int* __restrict__ row, int* __restrict__ cursor,
                          int* __restrict__ csr_src) {
    int e = blockIdx.x * blockDim.x + threadIdx.x;
    if (e >= E_TOT) return;
    int s, d; edge_sd(e, src, dst, s, d);
    int slot = row[d] + atomicAdd(&cursor[d], 1);
    csr_src[slot] = s;
}

// ====== Layer 1 GEMM: one wave per node; lane<48 computes 2 features ======
__global__ __launch_bounds__(256) void l1_gemm(const float* __restrict__ x,
                                               const float* __restrict__ W1,
                                               const float* __restrict__ attS,
                                               const float* __restrict__ attD,
                                               float* __restrict__ h1,
                                               float* __restrict__ aS1p,
                                               float* __restrict__ aD1p) {
    __shared__ float xs[4][F_IN];
    int wv = threadIdx.x >> 6, lane = threadIdx.x & 63;
    int n = blockIdx.x * 4 + wv;
    // stage x row: 64 lanes x float2 = 128 floats (wave-coherent, no barrier)
    *(float2*)&xs[wv][lane * 2] = *(const float2*)&x[n * F_IN + lane * 2];
    int f0 = (lane < 48) ? lane * 2 : 0;
    float acc0 = 0.f, acc1 = 0.f;
    const float* wp = W1 + f0;
#pragma unroll 4
    for (int k = 0; k < F_IN; k += 4) {
        float4 xv = *(const float4*)&xs[wv][k];
        float2 w0 = *(const float2*)&wp[(k + 0) * C1];
        float2 w1 = *(const float2*)&wp[(k + 1) * C1];
        float2 w2 = *(const float2*)&wp[(k + 2) * C1];
        float2 w3 = *(const float2*)&wp[(k + 3) * C1];
        acc0 = fmaf(xv.x, w0.x, acc0); acc1 = fmaf(xv.x, w0.y, acc1);
        acc0 = fmaf(xv.y, w1.x, acc0); acc1 = fmaf(xv.y, w1.y, acc1);
        acc0 = fmaf(xv.z, w2.x, acc0); acc1 = fmaf(xv.z, w2.y, acc1);
        acc0 = fmaf(xv.w, w3.x, acc0); acc1 = fmaf(xv.w, w3.y, acc1);
    }
    if (lane < 48) {
        float2 hv; hv.x = acc0; hv.y = acc1;
        *(float2*)&h1[n * C1 + f0] = hv;
        float ps = acc0 * attS[f0] + acc1 * attS[f0 + 1];
        float pd = acc0 * attD[f0] + acc1 * attD[f0 + 1];
#pragma unroll
        for (int o = 1; o < 16; o <<= 1) {
            ps += __shfl_xor(ps, o);
            pd += __shfl_xor(pd, o);
        }
        if ((lane & 15) == 0) {
            int h = lane >> 4;
            aS1p[n * 4 + h] = ps;
            aD1p[n * 4 + h] = pd;
        }
    }
}

// ===== Layer 1 fused softmax+aggregate: 1 wave/node, single pass, LDS-staged e =====
__global__ __launch_bounds__(256) void l1_node(const int* __restrict__ row,
                                               const int* __restrict__ csr,
                                               const float* __restrict__ h1,
                                               const float* __restrict__ aS1p,
                                               const float* __restrict__ aD1p,
                                               const float* __restrict__ bias1,
                                               float* __restrict__ hout) {
    __shared__ float lds[4][3][65][2];   // [wave][head][entry(+pad)][{e, src}]
    int wv = threadIdx.x >> 6, lane = threadIdx.x & 63;
    int n = blockIdx.x * 4 + wv;
    int rs = row[n], re = row[n + 1];
    float4 adv = *(const float4*)&aD1p[n * 4];
    int f0 = (lane < 48) ? lane * 2 : 0;
    int hh = lane >> 4; if (hh > 2) hh = 2;
    float d0 = 0.f, d1 = 0.f, d2 = 0.f;
    float acc0 = 0.f, acc1 = 0.f;
    for (int base = rs; base < re; base += 64) {
        int j = base + lane;
        if (j < re) {
            int s = csr[j];
            float4 a = *(const float4*)&aS1p[s * 4];
            float e0 = __expf(lrelu(a.x + adv.x));
            float e1 = __expf(lrelu(a.y + adv.y));
            float e2 = __expf(lrelu(a.z + adv.z));
            d0 += e0; d1 += e1; d2 += e2;
            float sf = __int_as_float(s);
            lds[wv][0][lane][0] = e0; lds[wv][0][lane][1] = sf;
            lds[wv][1][lane][0] = e1; lds[wv][1][lane][1] = sf;
            lds[wv][2][lane][0] = e2; lds[wv][2][lane][1] = sf;
        }
        int cnt = min(64, re - base);
#pragma unroll 2
        for (int j2 = 0; j2 < cnt; ++j2) {
            float2 es = *(const float2*)&lds[wv][hh][j2][0];
            int s = __float_as_int(es.y);
            float2 hv = *(const float2*)&h1[s * C1 + f0];
            acc0 = fmaf(hv.x, es.x, acc0);
            acc1 = fmaf(hv.y, es.x, acc1);
        }
    }
    d0 = wave_sum(d0); d1 = wave_sum(d1); d2 = wave_sum(d2);
    if (lane < 48) {
        float den = (hh == 0) ? d0 : (hh == 1) ? d1 : d2;
        float r = 1.f / den;
        float v0 = acc0 * r + bias1[f0];
        float v1 = acc1 * r + bias1[f0 + 1];
        float2 o;
        o.x = v0 > 0.f ? v0 : 0.f;
        o.y = v1 > 0.f ? v1 : 0.f;
        *(float2*)&hout[n * C1 + f0] = o;
    }
}

// ====== Layer 2 GEMM + att dots fused: 1 wave per node ======
__global__ __launch_bounds__(256) void l2_mix(const float* __restrict__ hmid,
                                              const float* __restrict__ W2,
                                              const float* __restrict__ attS,
                                              const float* __restrict__ attD,
                                              float* __restrict__ h2,
                                              float* __restrict__ aS2,
                                              float* __restrict__ aD2) {
    __shared__ float w[C1 * 17];         // W2 bank-padded [96][17]
    __shared__ float xs[4][100];         // hmid rows (pad 96->100)
    for (int i = threadIdx.x; i < C1 * OUT_F; i += 256)
        w[(i >> 4) * 17 + (i & 15)] = W2[i];
    __syncthreads();
    int wv = threadIdx.x >> 6, lane = threadIdx.x & 63;
    int n = blockIdx.x * 4 + wv;
    if (lane < 48)
        *(float2*)&xs[wv][lane * 2] = *(const float2*)&hmid[n * C1 + lane * 2];
    int g = lane >> 4, o = lane & 15;
    float acc = 0.f;
#pragma unroll 4
    for (int kk = 0; kk < 24; ++kk) {
        int k = g * 24 + kk;
        acc = fmaf(xs[wv][k], w[k * 17 + o], acc);
    }
    acc += __shfl_xor(acc, 16);
    acc += __shfl_xor(acc, 32);
    // every lane now holds h2[n][o]
    float ps = acc * attS[o];
    float pd = acc * attD[o];
#pragma unroll
    for (int s = 1; s < 16; s <<= 1) {
        ps += __shfl_xor(ps, s);
        pd += __shfl_xor(pd, s);
    }
    if (lane == 0) { aS2[n] = ps; aD2[n] = pd; }
    if (lane < 16) h2[n * OUT_F + o] = acc;
}

// ===== Layer 2 fused softmax+aggregate+bias+log_softmax: 1 wave/node =====
__global__ __launch_bounds__(256) void l2_node(const int* __restrict__ row,
                                               const int* __restrict__ csr,
                                               const float* __restrict__ h2,
                                               const float* __restrict__ aS2,
                                               const float* __restrict__ aD2,
                                               const float* __restrict__ bias2,
                                               float* __restrict__ out) {
    __shared__ float lds[4][64][2];      // [wave][entry][{e, src}]
    int wv = threadIdx.x >> 6, lane = threadIdx.x & 63;
    int n = blockIdx.x * 4 + wv;
    int rs = row[n], re = row[n + 1];
    float adn = aD2[n];
    int g = lane >> 4, fl = lane & 15;
    float den = 0.f, acc = 0.f;
    for (int base = rs; base < re; base += 64) {
        int j = base + lane;
        if (j < re) {
            int s = csr[j];
            float e = __expf(lrelu(aS2[s] + adn));
            den += e;
            lds[wv][lane][0] = e;
            lds[wv][lane][1] = __int_as_float(s);
        }
        int cnt = min(64, re - base);
#pragma unroll 2
        for (int j2 = g; j2 < cnt; j2 += 4) {
            float2 es = *(const float2*)&lds[wv][j2][0];
            int s = __float_as_int(es.y);
            acc = fmaf(h2[s * OUT_F + fl], es.x, acc);
        }
    }
    den = wave_sum(den);
    acc += __shfl_xor(acc, 16);
    acc += __shfl_xor(acc, 32);
    float v = acc / den + bias2[fl];
    // log_softmax over the 16 features (within each 16-lane group)
    float mm = v;
#pragma unroll
    for (int o = 1; o < 16; o <<= 1) mm = fmaxf(mm, __shfl_xor(mm, o));
    float se = __expf(v - mm);
#pragma unroll
    for (int o = 1; o < 16; o <<= 1) se += __shfl_xor(se, o);
    float lse = mm + logf(se);
    if (lane < 16) out[n * OUT_F + fl] = v - lse;
}

extern "C" void kernel_launch(void* const* d_in, const int* in_sizes, int n_in,
                              void* d_out, int out_size, void* d_ws, size_t ws_size,
                              hipStream_t stream) {
    const float* x      = (const float*)d_in[0];
    const int*   ei     = (const int*)  d_in[1];
    const float* W1     = (const float*)d_in[2];
    const float* attS1  = (const float*)d_in[3];
    const float* attD1  = (const float*)d_in[4];
    const float* bias1  = (const float*)d_in[5];
    const float* W2     = (const float*)d_in[6];
    const float* attS2  = (const float*)d_in[7];
    const float* attD2  = (const float*)d_in[8];
    const float* bias2  = (const float*)d_in[9];
    const int* src = ei;
    const int* dst = ei + N_EDGES;
    float* out = (float*)d_out;
    (void)in_sizes; (void)n_in; (void)out_size; (void)ws_size;

    // ---- workspace layout ----
    char* wsb = (char*)d_ws;
    size_t off = 0;
    int* deg    = (int*)(wsb + off); off += (size_t)N_NODES * 4;
    int* cursor = (int*)(wsb + off); off += (size_t)N_NODES * 4;
    size_t zero_bytes = off;
    int* inc    = (int*)(wsb + off); off += (size_t)N_NODES * 4;
    int* bsum   = (int*)(wsb + off); off += 256 * 4;
    int* row    = (int*)(wsb + off); off += ((size_t)N_NODES + 1) * 4;
    // align to 16B
    off = (off + 15) & ~(size_t)15;
    int* csr    = (int*)(wsb + off); off += (size_t)E_TOT * 4;
    off = (off + 15) & ~(size_t)15;
    float* h1   = (float*)(wsb + off); off += (size_t)N_NODES * C1 * 4;
    float* aS1p = (float*)(wsb + off); off += (size_t)N_NODES * 4 * 4;
    float* aD1p = (float*)(wsb + off); off += (size_t)N_NODES * 4 * 4;
    float* hmid = (float*)(wsb + off); off += (size_t)N_NODES * C1 * 4;
    float* h2   = (float*)(wsb + off); off += (size_t)N_NODES * OUT_F * 4;
    float* aS2  = (float*)(wsb + off); off += (size_t)N_NODES * 4;
    float* aD2  = (float*)(wsb + off); off += (size_t)N_NODES * 4;

    hipMemsetAsync(d_ws, 0, zero_bytes, stream);

    int nbe = (E_TOT + 255) / 256;
    // CSR build
    k_deg<<<nbe, 256, 0, stream>>>(src, dst, deg);
    k_scan1<<<NB_SCAN, 256, 0, stream>>>(deg, inc, bsum);
    k_scan2<<<1, 256, 0, stream>>>(bsum);
    k_scan3<<<NB_SCAN, 256, 0, stream>>>(inc, bsum, row);
    k_scatter<<<nbe, 256, 0, stream>>>(src, dst, row, cursor, csr);

    int nbn = N_NODES / 4;   // 12500, exact
    // layer 1
    l1_gemm<<<nbn, 256, 0, stream>>>(x, W1, attS1, attD1, h1, aS1p, aD1p);
    l1_node<<<nbn, 256, 0, stream>>>(row, csr, h1, aS1p, aD1p, bias1, hmid);
    // layer 2
    l2_mix<<<nbn, 256, 0, stream>>>(hmid, W2, attS2, attD2, h2, aS2, aD2);
    l2_node<<<nbn, 256, 0, stream>>>(row, csr, h2, aS2, aD2, bias2, out);
}

// Round 5
// 383.757 us; speedup vs baseline: 3.5673x; 1.3705x over previous
//
#include <hip/hip_runtime.h>
#include <hip/hip_bf16.h>

#define N_NODES 50000
#define N_EDGES 1600000
#define E_TOT   1650000   // edges + self loops
#define F_IN    128
#define HID     32
#define HEADS   3
#define C1      96        // HEADS*HID
#define OUT_F   16
#define NEG_SLOPE 0.2f
#define NB_SCAN 196       // ceil(50000/256)
#define BM      64        // l1_gemm node tile

__device__ __forceinline__ float lrelu(float v) {
    return v > 0.f ? v : NEG_SLOPE * v;
}
__device__ __forceinline__ void edge_sd(int e, const int* __restrict__ src,
                                        const int* __restrict__ dst, int& s, int& d) {
    if (e < N_EDGES) { s = src[e]; d = dst[e]; }
    else { s = d = e - N_EDGES; }
}
__device__ __forceinline__ float wave_sum(float v) {
#pragma unroll
    for (int o = 32; o; o >>= 1) v += __shfl_xor(v, o);
    return v;
}

// ================= CSR construction =================
__global__ void k_deg(const int* __restrict__ src, const int* __restrict__ dst,
                      int* __restrict__ deg) {
    int e = blockIdx.x * blockDim.x + threadIdx.x;
    if (e >= E_TOT) return;
    int s, d; edge_sd(e, src, dst, s, d);
    atomicAdd(&deg[d], 1);
}

__global__ void k_scan1(const int* __restrict__ deg, int* __restrict__ inc,
                        int* __restrict__ bsum) {
    __shared__ int sh[256];
    int t = threadIdx.x;
    int i = blockIdx.x * 256 + t;
    int v = (i < N_NODES) ? deg[i] : 0;
    sh[t] = v; __syncthreads();
#pragma unroll
    for (int o = 1; o < 256; o <<= 1) {
        int u = (t >= o) ? sh[t - o] : 0;
        __syncthreads();
        sh[t] += u;
        __syncthreads();
    }
    if (i < N_NODES) inc[i] = sh[t];
    if (t == 255) bsum[blockIdx.x] = sh[255];
}

__global__ void k_scan2(int* __restrict__ bsum) {
    __shared__ int sh[256];
    int t = threadIdx.x;
    int v = (t < NB_SCAN) ? bsum[t] : 0;
    sh[t] = v; __syncthreads();
#pragma unroll
    for (int o = 1; o < 256; o <<= 1) {
        int u = (t >= o) ? sh[t - o] : 0;
        __syncthreads();
        sh[t] += u;
        __syncthreads();
    }
    if (t < NB_SCAN) bsum[t] = sh[t];
}

__global__ void k_scan3(const int* __restrict__ inc, const int* __restrict__ bsum,
                        int* __restrict__ row) {
    int i = blockIdx.x * blockDim.x + threadIdx.x;
    if (i < N_NODES) {
        int add = blockIdx.x ? bsum[blockIdx.x - 1] : 0;
        row[i + 1] = inc[i] + add;
    }
    if (i == 0) row[0] = 0;
}

__global__ void k_scatter(const int* __restrict__ src, const int* __restrict__ dst,
                          const int* __restrict__ row, int* __restrict__ cursor,
                          int* __restrict__ csr_src) {
    int e = blockIdx.x * blockDim.x + threadIdx.x;
    if (e >= E_TOT) return;
    int s, d; edge_sd(e, src, dst, s, d);
    int slot = row[d] + atomicAdd(&cursor[d], 1);
    csr_src[slot] = s;
}

// ====== Layer 1 GEMM: register-tiled. Block = 64 nodes x 96 feats. ======
// Thread (tx,ty): tx=t&15 owns features f=tx+16j (j=0..5, head=j>>1 compile-time),
// ty=t>>4 owns nodes n0+ty*4+i (i=0..3). 24 accumulators/thread for ILP.
__global__ __launch_bounds__(256) void l1_gemm(const float* __restrict__ x,
                                               const float* __restrict__ W1,
                                               const float* __restrict__ attS,
                                               const float* __restrict__ attD,
                                               float* __restrict__ h1,
                                               float* __restrict__ aS1p,
                                               float* __restrict__ aD1p) {
    __shared__ float xs[BM][F_IN + 4];   // stride 132: rows 4 banks apart
    int t = threadIdx.x;
    int tx = t & 15, ty = t >> 4;
    int n0 = blockIdx.x * BM;
    // stage x tile: 64 rows x 32 float4, 8 per thread, coalesced
    {
        const float4* xg = (const float4*)x;
#pragma unroll
        for (int it = 0; it < 8; ++it) {
            int idx = t + it * 256;
            int r = idx >> 5, c = idx & 31;
            int nn = n0 + r;
            float4 v = (nn < N_NODES) ? xg[nn * 32 + c]
                                      : make_float4(0.f, 0.f, 0.f, 0.f);
            *(float4*)&xs[r][c * 4] = v;
        }
    }
    __syncthreads();

    float acc[4][6];
#pragma unroll
    for (int i = 0; i < 4; ++i)
#pragma unroll
        for (int j = 0; j < 6; ++j) acc[i][j] = 0.f;

    int r0 = ty * 4;
    const float* wbase = W1 + tx;
#pragma unroll 4
    for (int k = 0; k < F_IN; k += 2) {
        float w0[6], w1[6];
#pragma unroll
        for (int j = 0; j < 6; ++j) {
            w0[j] = wbase[k * C1 + 16 * j];
            w1[j] = wbase[(k + 1) * C1 + 16 * j];
        }
        float2 xv[4];
#pragma unroll
        for (int i = 0; i < 4; ++i)
            xv[i] = *(const float2*)&xs[r0 + i][k];
#pragma unroll
        for (int i = 0; i < 4; ++i)
#pragma unroll
            for (int j = 0; j < 6; ++j) {
                acc[i][j] = fmaf(xv[i].x, w0[j], acc[i][j]);
                acc[i][j] = fmaf(xv[i].y, w1[j], acc[i][j]);
            }
    }

    // epilogue: h1 stores + per-head attention dots
    float as[6], ad[6];
#pragma unroll
    for (int j = 0; j < 6; ++j) {
        as[j] = attS[tx + 16 * j];
        ad[j] = attD[tx + 16 * j];
    }
#pragma unroll
    for (int i = 0; i < 4; ++i) {
        int n = n0 + r0 + i;
        bool ok = (n < N_NODES);
        float ps0 = 0.f, ps1 = 0.f, ps2 = 0.f, pd0 = 0.f, pd1 = 0.f, pd2 = 0.f;
#pragma unroll
        for (int j = 0; j < 6; ++j) {
            if (ok) h1[n * C1 + tx + 16 * j] = acc[i][j];
            float vs = acc[i][j] * as[j], vd = acc[i][j] * ad[j];
            if (j < 2)      { ps0 += vs; pd0 += vd; }
            else if (j < 4) { ps1 += vs; pd1 += vd; }
            else            { ps2 += vs; pd2 += vd; }
        }
#pragma unroll
        for (int o = 1; o < 16; o <<= 1) {
            ps0 += __shfl_xor(ps0, o); pd0 += __shfl_xor(pd0, o);
            ps1 += __shfl_xor(ps1, o); pd1 += __shfl_xor(pd1, o);
            ps2 += __shfl_xor(ps2, o); pd2 += __shfl_xor(pd2, o);
        }
        if (ok && tx == 0) {
            aS1p[n * 4 + 0] = ps0; aS1p[n * 4 + 1] = ps1; aS1p[n * 4 + 2] = ps2;
            aS1p[n * 4 + 3] = 0.f;
            aD1p[n * 4 + 0] = pd0; aD1p[n * 4 + 1] = pd1; aD1p[n * 4 + 2] = pd2;
            aD1p[n * 4 + 3] = 0.f;
        }
    }
}

// ===== Layer 1 fused softmax+aggregate: 1 wave/node, single pass, LDS-staged e =====
__global__ __launch_bounds__(256) void l1_node(const int* __restrict__ row,
                                               const int* __restrict__ csr,
                                               const float* __restrict__ h1,
                                               const float* __restrict__ aS1p,
                                               const float* __restrict__ aD1p,
                                               const float* __restrict__ bias1,
                                               float* __restrict__ hout) {
    __shared__ float lds[4][3][65][2];   // [wave][head][entry(+pad)][{e, src}]
    int wv = threadIdx.x >> 6, lane = threadIdx.x & 63;
    int n = blockIdx.x * 4 + wv;
    int rs = row[n], re = row[n + 1];
    float4 adv = *(const float4*)&aD1p[n * 4];
    int f0 = (lane < 48) ? lane * 2 : 0;
    int hh = lane >> 4; if (hh > 2) hh = 2;
    float d0 = 0.f, d1 = 0.f, d2 = 0.f;
    float acc0 = 0.f, acc1 = 0.f;
    for (int base = rs; base < re; base += 64) {
        int j = base + lane;
        if (j < re) {
            int s = csr[j];
            float4 a = *(const float4*)&aS1p[s * 4];
            float e0 = __expf(lrelu(a.x + adv.x));
            float e1 = __expf(lrelu(a.y + adv.y));
            float e2 = __expf(lrelu(a.z + adv.z));
            d0 += e0; d1 += e1; d2 += e2;
            float sf = __int_as_float(s);
            lds[wv][0][lane][0] = e0; lds[wv][0][lane][1] = sf;
            lds[wv][1][lane][0] = e1; lds[wv][1][lane][1] = sf;
            lds[wv][2][lane][0] = e2; lds[wv][2][lane][1] = sf;
        }
        int cnt = min(64, re - base);
#pragma unroll 2
        for (int j2 = 0; j2 < cnt; ++j2) {
            float2 es = *(const float2*)&lds[wv][hh][j2][0];
            int s = __float_as_int(es.y);
            float2 hv = *(const float2*)&h1[s * C1 + f0];
            acc0 = fmaf(hv.x, es.x, acc0);
            acc1 = fmaf(hv.y, es.x, acc1);
        }
    }
    d0 = wave_sum(d0); d1 = wave_sum(d1); d2 = wave_sum(d2);
    if (lane < 48) {
        float den = (hh == 0) ? d0 : (hh == 1) ? d1 : d2;
        float r = 1.f / den;
        float v0 = acc0 * r + bias1[f0];
        float v1 = acc1 * r + bias1[f0 + 1];
        float2 o;
        o.x = v0 > 0.f ? v0 : 0.f;
        o.y = v1 > 0.f ? v1 : 0.f;
        *(float2*)&hout[n * C1 + f0] = o;
    }
}

// ====== Layer 2 GEMM + att dots fused: 1 wave per node ======
__global__ __launch_bounds__(256) void l2_mix(const float* __restrict__ hmid,
                                              const float* __restrict__ W2,
                                              const float* __restrict__ attS,
                                              const float* __restrict__ attD,
                                              float* __restrict__ h2,
                                              float* __restrict__ aS2,
                                              float* __restrict__ aD2) {
    __shared__ float w[C1 * 17];         // W2 bank-padded [96][17]
    __shared__ float xs[4][100];         // hmid rows (pad 96->100)
    for (int i = threadIdx.x; i < C1 * OUT_F; i += 256)
        w[(i >> 4) * 17 + (i & 15)] = W2[i];
    __syncthreads();
    int wv = threadIdx.x >> 6, lane = threadIdx.x & 63;
    int n = blockIdx.x * 4 + wv;
    if (lane < 48)
        *(float2*)&xs[wv][lane * 2] = *(const float2*)&hmid[n * C1 + lane * 2];
    int g = lane >> 4, o = lane & 15;
    float acc = 0.f;
#pragma unroll 4
    for (int kk = 0; kk < 24; ++kk) {
        int k = g * 24 + kk;
        acc = fmaf(xs[wv][k], w[k * 17 + o], acc);
    }
    acc += __shfl_xor(acc, 16);
    acc += __shfl_xor(acc, 32);
    // every lane now holds h2[n][o]
    float ps = acc * attS[o];
    float pd = acc * attD[o];
#pragma unroll
    for (int s = 1; s < 16; s <<= 1) {
        ps += __shfl_xor(ps, s);
        pd += __shfl_xor(pd, s);
    }
    if (lane == 0) { aS2[n] = ps; aD2[n] = pd; }
    if (lane < 16) h2[n * OUT_F + o] = acc;
}

// ===== Layer 2 fused softmax+aggregate+bias+log_softmax: 1 wave/node =====
__global__ __launch_bounds__(256) void l2_node(const int* __restrict__ row,
                                               const int* __restrict__ csr,
                                               const float* __restrict__ h2,
                                               const float* __restrict__ aS2,
                                               const float* __restrict__ aD2,
                                               const float* __restrict__ bias2,
                                               float* __restrict__ out) {
    __shared__ float lds[4][64][2];      // [wave][entry][{e, src}]
    int wv = threadIdx.x >> 6, lane = threadIdx.x & 63;
    int n = blockIdx.x * 4 + wv;
    int rs = row[n], re = row[n + 1];
    float adn = aD2[n];
    int g = lane >> 4, fl = lane & 15;
    float den = 0.f, acc = 0.f;
    for (int base = rs; base < re; base += 64) {
        int j = base + lane;
        if (j < re) {
            int s = csr[j];
            float e = __expf(lrelu(aS2[s] + adn));
            den += e;
            lds[wv][lane][0] = e;
            lds[wv][lane][1] = __int_as_float(s);
        }
        int cnt = min(64, re - base);
#pragma unroll 2
        for (int j2 = g; j2 < cnt; j2 += 4) {
            float2 es = *(const float2*)&lds[wv][j2][0];
            int s = __float_as_int(es.y);
            acc = fmaf(h2[s * OUT_F + fl], es.x, acc);
        }
    }
    den = wave_sum(den);
    acc += __shfl_xor(acc, 16);
    acc += __shfl_xor(acc, 32);
    float v = acc / den + bias2[fl];
    // log_softmax over the 16 features (within each 16-lane group)
    float mm = v;
#pragma unroll
    for (int o = 1; o < 16; o <<= 1) mm = fmaxf(mm, __shfl_xor(mm, o));
    float se = __expf(v - mm);
#pragma unroll
    for (int o = 1; o < 16; o <<= 1) se += __shfl_xor(se, o);
    float lse = mm + logf(se);
    if (lane < 16) out[n * OUT_F + fl] = v - lse;
}

extern "C" void kernel_launch(void* const* d_in, const int* in_sizes, int n_in,
                              void* d_out, int out_size, void* d_ws, size_t ws_size,
                              hipStream_t stream) {
    const float* x      = (const float*)d_in[0];
    const int*   ei     = (const int*)  d_in[1];
    const float* W1     = (const float*)d_in[2];
    const float* attS1  = (const float*)d_in[3];
    const float* attD1  = (const float*)d_in[4];
    const float* bias1  = (const float*)d_in[5];
    const float* W2     = (const float*)d_in[6];
    const float* attS2  = (const float*)d_in[7];
    const float* attD2  = (const float*)d_in[8];
    const float* bias2  = (const float*)d_in[9];
    const int* src = ei;
    const int* dst = ei + N_EDGES;
    float* out = (float*)d_out;
    (void)in_sizes; (void)n_in; (void)out_size; (void)ws_size;

    // ---- workspace layout ----
    char* wsb = (char*)d_ws;
    size_t off = 0;
    int* deg    = (int*)(wsb + off); off += (size_t)N_NODES * 4;
    int* cursor = (int*)(wsb + off); off += (size_t)N_NODES * 4;
    size_t zero_bytes = off;
    int* inc    = (int*)(wsb + off); off += (size_t)N_NODES * 4;
    int* bsum   = (int*)(wsb + off); off += 256 * 4;
    int* row    = (int*)(wsb + off); off += ((size_t)N_NODES + 1) * 4;
    off = (off + 15) & ~(size_t)15;
    int* csr    = (int*)(wsb + off); off += (size_t)E_TOT * 4;
    off = (off + 15) & ~(size_t)15;
    float* h1   = (float*)(wsb + off); off += (size_t)N_NODES * C1 * 4;
    float* aS1p = (float*)(wsb + off); off += (size_t)N_NODES * 4 * 4;
    float* aD1p = (float*)(wsb + off); off += (size_t)N_NODES * 4 * 4;
    float* hmid = (float*)(wsb + off); off += (size_t)N_NODES * C1 * 4;
    float* h2   = (float*)(wsb + off); off += (size_t)N_NODES * OUT_F * 4;
    float* aS2  = (float*)(wsb + off); off += (size_t)N_NODES * 4;
    float* aD2  = (float*)(wsb + off); off += (size_t)N_NODES * 4;

    hipMemsetAsync(d_ws, 0, zero_bytes, stream);

    int nbe = (E_TOT + 255) / 256;
    // CSR build
    k_deg<<<nbe, 256, 0, stream>>>(src, dst, deg);
    k_scan1<<<NB_SCAN, 256, 0, stream>>>(deg, inc, bsum);
    k_scan2<<<1, 256, 0, stream>>>(bsum);
    k_scan3<<<NB_SCAN, 256, 0, stream>>>(inc, bsum, row);
    k_scatter<<<nbe, 256, 0, stream>>>(src, dst, row, cursor, csr);

    int nbn = N_NODES / 4;   // 12500, exact
    // layer 1
    int nbg = (N_NODES + BM - 1) / BM;   // 782
    l1_gemm<<<nbg, 256, 0, stream>>>(x, W1, attS1, attD1, h1, aS1p, aD1p);
    l1_node<<<nbn, 256, 0, stream>>>(row, csr, h1, aS1p, aD1p, bias1, hmid);
    // layer 2
    l2_mix<<<nbn, 256, 0, stream>>>(hmid, W2, attS2, attD2, h2, aS2, aD2);
    l2_node<<<nbn, 256, 0, stream>>>(row, csr, h2, aS2, aD2, bias2, out);
}

// Round 7
// 234.906 us; speedup vs baseline: 5.8278x; 1.6337x over previous
//
#include <hip/hip_runtime.h>
#include <hip/hip_bf16.h>

#define N_NODES 50000
#define N_EDGES 1600000
#define E_TOT   1650000   // edges + self loops
#define F_IN    128
#define HID     32
#define HEADS   3
#define C1      96        // HEADS*HID
#define OUT_F   16
#define NEG_SLOPE 0.2f
#define NB_SCAN 196       // ceil(50000/256)
#define BM      64        // l1_gemm node tile
#define NBUCK   196       // CSR coarse buckets: bucket = dst >> 8 (256 nodes each)
#define CHUNK   4096      // edges per block in bucket passes
#define NBLK_B  403       // ceil(E_TOT / CHUNK)

typedef __hip_bfloat16  bf16;
typedef __hip_bfloat162 bf162;

__device__ __forceinline__ float lrelu(float v) {
    return v > 0.f ? v : NEG_SLOPE * v;
}
__device__ __forceinline__ float wave_sum(float v) {
#pragma unroll
    for (int o = 32; o; o >>= 1) v += __shfl_xor(v, o);
    return v;
}

// ================= CSR construction: bucketed counting sort =================
// Pass A: histogram of coarse buckets (dst>>8)
__global__ __launch_bounds__(256) void k_bhist(const int* __restrict__ dst,
                                               int* __restrict__ bcnt) {
    __shared__ int h[NBUCK];
    for (int i = threadIdx.x; i < NBUCK; i += 256) h[i] = 0;
    __syncthreads();
    int base = blockIdx.x * CHUNK;
    int end = min(base + CHUNK, E_TOT);
    for (int e = base + threadIdx.x; e < end; e += 256) {
        int d = (e < N_EDGES) ? dst[e] : e - N_EDGES;
        atomicAdd(&h[d >> 8], 1);
    }
    __syncthreads();
    for (int i = threadIdx.x; i < NBUCK; i += 256)
        if (h[i]) atomicAdd(&bcnt[i], h[i]);
}

// Pass B: exclusive scan of bucket counts; seed cursors
__global__ __launch_bounds__(256) void k_bscan(const int* __restrict__ bcnt,
                                               int* __restrict__ boff,
                                               int* __restrict__ bcur) {
    __shared__ int sh[256];
    int t = threadIdx.x;
    int v = (t < NBUCK) ? bcnt[t] : 0;
    sh[t] = v; __syncthreads();
#pragma unroll
    for (int o = 1; o < 256; o <<= 1) {
        int u = (t >= o) ? sh[t - o] : 0;
        __syncthreads();
        sh[t] += u;
        __syncthreads();
    }
    int ex = sh[t] - v;
    if (t < NBUCK) { boff[t] = ex; bcur[t] = ex; }
    if (t == NBUCK - 1) boff[NBUCK] = sh[t];
}

// Pass C: scatter (src,dst) pairs into contiguous bucket runs
__global__ __launch_bounds__(256) void k_bucket(const int* __restrict__ src,
                                                const int* __restrict__ dst,
                                                int* __restrict__ bcur,
                                                int2* __restrict__ bedge) {
    __shared__ int h[NBUCK], cur[NBUCK];
    for (int i = threadIdx.x; i < NBUCK; i += 256) h[i] = 0;
    __syncthreads();
    int base = blockIdx.x * CHUNK;
    int end = min(base + CHUNK, E_TOT);
    for (int e = base + threadIdx.x; e < end; e += 256) {
        int d = (e < N_EDGES) ? dst[e] : e - N_EDGES;
        atomicAdd(&h[d >> 8], 1);
    }
    __syncthreads();
    for (int i = threadIdx.x; i < NBUCK; i += 256)
        cur[i] = h[i] ? atomicAdd(&bcur[i], h[i]) : 0;
    __syncthreads();
    for (int e = base + threadIdx.x; e < end; e += 256) {
        int s, d;
        if (e < N_EDGES) { s = src[e]; d = dst[e]; }
        else { s = d = e - N_EDGES; }
        int slot = atomicAdd(&cur[d >> 8], 1);
        bedge[slot] = make_int2(s, d);
    }
}

// Pass D: per-bucket node histogram -> deg (coalesced write)
__global__ __launch_bounds__(256) void k_deg2(const int* __restrict__ boff,
                                              const int2* __restrict__ bedge,
                                              int* __restrict__ deg) {
    __shared__ int h[256];
    int b = blockIdx.x, t = threadIdx.x;
    h[t] = 0; __syncthreads();
    int s0 = boff[b], s1 = boff[b + 1];
    for (int i = s0 + t; i < s1; i += 256)
        atomicAdd(&h[bedge[i].y & 255], 1);
    __syncthreads();
    int n = b * 256 + t;
    if (n < N_NODES) deg[n] = h[t];
}

// ---- node-level scan over deg ----
__global__ void k_scan1(const int* __restrict__ deg, int* __restrict__ inc,
                        int* __restrict__ bsum) {
    __shared__ int sh[256];
    int t = threadIdx.x;
    int i = blockIdx.x * 256 + t;
    int v = (i < N_NODES) ? deg[i] : 0;
    sh[t] = v; __syncthreads();
#pragma unroll
    for (int o = 1; o < 256; o <<= 1) {
        int u = (t >= o) ? sh[t - o] : 0;
        __syncthreads();
        sh[t] += u;
        __syncthreads();
    }
    if (i < N_NODES) inc[i] = sh[t];
    if (t == 255) bsum[blockIdx.x] = sh[255];
}

__global__ void k_scan2(int* __restrict__ bsum) {
    __shared__ int sh[256];
    int t = threadIdx.x;
    int v = (t < NB_SCAN) ? bsum[t] : 0;
    sh[t] = v; __syncthreads();
#pragma unroll
    for (int o = 1; o < 256; o <<= 1) {
        int u = (t >= o) ? sh[t - o] : 0;
        __syncthreads();
        sh[t] += u;
        __syncthreads();
    }
    if (t < NB_SCAN) bsum[t] = sh[t];
}

__global__ void k_scan3(const int* __restrict__ inc, const int* __restrict__ bsum,
                        int* __restrict__ row) {
    int i = blockIdx.x * blockDim.x + threadIdx.x;
    if (i < N_NODES) {
        int add = blockIdx.x ? bsum[blockIdx.x - 1] : 0;
        row[i + 1] = inc[i] + add;
    }
    if (i == 0) row[0] = 0;
}

// Pass E: final scatter within bucket -> csr (contiguous per-block output region)
__global__ __launch_bounds__(256) void k_scatter2(const int* __restrict__ boff,
                                                  const int2* __restrict__ bedge,
                                                  const int* __restrict__ row,
                                                  int* __restrict__ csr) {
    __shared__ int cur[256];
    int b = blockIdx.x, t = threadIdx.x;
    int n = b * 256 + t;
    cur[t] = (n < N_NODES) ? row[n] : 0;
    __syncthreads();
    int s0 = boff[b], s1 = boff[b + 1];
    for (int i = s0 + t; i < s1; i += 256) {
        int2 e = bedge[i];
        int slot = atomicAdd(&cur[e.y & 255], 1);
        csr[slot] = e.x;
    }
}

// ====== Layer 1 GEMM: register-tiled. Block = 64 nodes x 96 feats. h1 -> bf16 ======
__global__ __launch_bounds__(256) void l1_gemm(const float* __restrict__ x,
                                               const float* __restrict__ W1,
                                               const float* __restrict__ attS,
                                               const float* __restrict__ attD,
                                               bf16* __restrict__ h1,
                                               float* __restrict__ aS1p,
                                               float* __restrict__ aD1p) {
    __shared__ float xs[BM][F_IN + 4];   // stride 132: rows 4 banks apart
    int t = threadIdx.x;
    int tx = t & 15, ty = t >> 4;
    int n0 = blockIdx.x * BM;
    {
        const float4* xg = (const float4*)x;
#pragma unroll
        for (int it = 0; it < 8; ++it) {
            int idx = t + it * 256;
            int r = idx >> 5, c = idx & 31;
            int nn = n0 + r;
            float4 v = (nn < N_NODES) ? xg[nn * 32 + c]
                                      : make_float4(0.f, 0.f, 0.f, 0.f);
            *(float4*)&xs[r][c * 4] = v;
        }
    }
    __syncthreads();

    float acc[4][6];
#pragma unroll
    for (int i = 0; i < 4; ++i)
#pragma unroll
        for (int j = 0; j < 6; ++j) acc[i][j] = 0.f;

    int r0 = ty * 4;
    const float* wbase = W1 + tx;
#pragma unroll 4
    for (int k = 0; k < F_IN; k += 2) {
        float w0[6], w1[6];
#pragma unroll
        for (int j = 0; j < 6; ++j) {
            w0[j] = wbase[k * C1 + 16 * j];
            w1[j] = wbase[(k + 1) * C1 + 16 * j];
        }
        float2 xv[4];
#pragma unroll
        for (int i = 0; i < 4; ++i)
            xv[i] = *(const float2*)&xs[r0 + i][k];
#pragma unroll
        for (int i = 0; i < 4; ++i)
#pragma unroll
            for (int j = 0; j < 6; ++j) {
                acc[i][j] = fmaf(xv[i].x, w0[j], acc[i][j]);
                acc[i][j] = fmaf(xv[i].y, w1[j], acc[i][j]);
            }
    }

    float as[6], ad[6];
#pragma unroll
    for (int j = 0; j < 6; ++j) {
        as[j] = attS[tx + 16 * j];
        ad[j] = attD[tx + 16 * j];
    }
#pragma unroll
    for (int i = 0; i < 4; ++i) {
        int n = n0 + r0 + i;
        bool ok = (n < N_NODES);
        float ps0 = 0.f, ps1 = 0.f, ps2 = 0.f, pd0 = 0.f, pd1 = 0.f, pd2 = 0.f;
#pragma unroll
        for (int j = 0; j < 6; ++j) {
            if (ok) h1[n * C1 + tx + 16 * j] = __float2bfloat16(acc[i][j]);
            float vs = acc[i][j] * as[j], vd = acc[i][j] * ad[j];
            if (j < 2)      { ps0 += vs; pd0 += vd; }
            else if (j < 4) { ps1 += vs; pd1 += vd; }
            else            { ps2 += vs; pd2 += vd; }
        }
#pragma unroll
        for (int o = 1; o < 16; o <<= 1) {
            ps0 += __shfl_xor(ps0, o); pd0 += __shfl_xor(pd0, o);
            ps1 += __shfl_xor(ps1, o); pd1 += __shfl_xor(pd1, o);
            ps2 += __shfl_xor(ps2, o); pd2 += __shfl_xor(pd2, o);
        }
        if (ok && tx == 0) {
            aS1p[n * 4 + 0] = ps0; aS1p[n * 4 + 1] = ps1; aS1p[n * 4 + 2] = ps2;
            aS1p[n * 4 + 3] = 0.f;
            aD1p[n * 4 + 0] = pd0; aD1p[n * 4 + 1] = pd1; aD1p[n * 4 + 2] = pd2;
            aD1p[n * 4 + 3] = 0.f;
        }
    }
}

// ===== Layer 1 fused softmax+aggregate: 1 wave/node, bf16 h1 gather =====
__global__ __launch_bounds__(256) void l1_node(const int* __restrict__ row,
                                               const int* __restrict__ csr,
                                               const bf16* __restrict__ h1,
                                               const float* __restrict__ aS1p,
                                               const float* __restrict__ aD1p,
                                               const float* __restrict__ bias1,
                                               float* __restrict__ hout) {
    __shared__ float lds[4][3][65][2];   // [wave][head][entry(+pad)][{e, src}]
    int wv = threadIdx.x >> 6, lane = threadIdx.x & 63;
    int n = blockIdx.x * 4 + wv;
    int rs = row[n], re = row[n + 1];
    float4 adv = *(const float4*)&aD1p[n * 4];
    int f0 = (lane < 48) ? lane * 2 : 0;
    int hh = lane >> 4; if (hh > 2) hh = 2;
    float d0 = 0.f, d1 = 0.f, d2 = 0.f;
    float acc0 = 0.f, acc1 = 0.f;
    for (int base = rs; base < re; base += 64) {
        int j = base + lane;
        if (j < re) {
            int s = csr[j];
            float4 a = *(const float4*)&aS1p[s * 4];
            float e0 = __expf(lrelu(a.x + adv.x));
            float e1 = __expf(lrelu(a.y + adv.y));
            float e2 = __expf(lrelu(a.z + adv.z));
            d0 += e0; d1 += e1; d2 += e2;
            float sf = __int_as_float(s);
            lds[wv][0][lane][0] = e0; lds[wv][0][lane][1] = sf;
            lds[wv][1][lane][0] = e1; lds[wv][1][lane][1] = sf;
            lds[wv][2][lane][0] = e2; lds[wv][2][lane][1] = sf;
        }
        int cnt = min(64, re - base);
#pragma unroll 2
        for (int j2 = 0; j2 < cnt; ++j2) {
            float2 es = *(const float2*)&lds[wv][hh][j2][0];
            int s = __float_as_int(es.y);
            bf162 hb = *(const bf162*)&h1[s * C1 + f0];
            float2 hv = __bfloat1622float2(hb);
            acc0 = fmaf(hv.x, es.x, acc0);
            acc1 = fmaf(hv.y, es.x, acc1);
        }
    }
    d0 = wave_sum(d0); d1 = wave_sum(d1); d2 = wave_sum(d2);
    if (lane < 48) {
        float den = (hh == 0) ? d0 : (hh == 1) ? d1 : d2;
        float r = 1.f / den;
        float v0 = acc0 * r + bias1[f0];
        float v1 = acc1 * r + bias1[f0 + 1];
        float2 o;
        o.x = v0 > 0.f ? v0 : 0.f;
        o.y = v1 > 0.f ? v1 : 0.f;
        *(float2*)&hout[n * C1 + f0] = o;
    }
}

// ====== Layer 2 GEMM + att dots fused: 1 wave per node ======
__global__ __launch_bounds__(256) void l2_mix(const float* __restrict__ hmid,
                                              const float* __restrict__ W2,
                                              const float* __restrict__ attS,
                                              const float* __restrict__ attD,
                                              float* __restrict__ h2,
                                              float* __restrict__ aS2,
                                              float* __restrict__ aD2) {
    __shared__ float w[C1 * 17];         // W2 bank-padded [96][17]
    __shared__ float xs[4][100];         // hmid rows (pad 96->100)
    for (int i = threadIdx.x; i < C1 * OUT_F; i += 256)
        w[(i >> 4) * 17 + (i & 15)] = W2[i];
    __syncthreads();
    int wv = threadIdx.x >> 6, lane = threadIdx.x & 63;
    int n = blockIdx.x * 4 + wv;
    if (lane < 48)
        *(float2*)&xs[wv][lane * 2] = *(const float2*)&hmid[n * C1 + lane * 2];
    int g = lane >> 4, o = lane & 15;
    float acc = 0.f;
#pragma unroll 4
    for (int kk = 0; kk < 24; ++kk) {
        int k = g * 24 + kk;
        acc = fmaf(xs[wv][k], w[k * 17 + o], acc);
    }
    acc += __shfl_xor(acc, 16);
    acc += __shfl_xor(acc, 32);
    float ps = acc * attS[o];
    float pd = acc * attD[o];
#pragma unroll
    for (int s = 1; s < 16; s <<= 1) {
        ps += __shfl_xor(ps, s);
        pd += __shfl_xor(pd, s);
    }
    if (lane == 0) { aS2[n] = ps; aD2[n] = pd; }
    if (lane < 16) h2[n * OUT_F + o] = acc;
}

// ===== Layer 2 fused softmax+aggregate+bias+log_softmax: 1 wave/node =====
__global__ __launch_bounds__(256) void l2_node(const int* __restrict__ row,
                                               const int* __restrict__ csr,
                                               const float* __restrict__ h2,
                                               const float* __restrict__ aS2,
                                               const float* __restrict__ aD2,
                                               const float* __restrict__ bias2,
                                               float* __restrict__ out) {
    __shared__ float lds[4][64][2];      // [wave][entry][{e, src}]
    int wv = threadIdx.x >> 6, lane = threadIdx.x & 63;
    int n = blockIdx.x * 4 + wv;
    int rs = row[n], re = row[n + 1];
    float adn = aD2[n];
    int g = lane >> 4, fl = lane & 15;
    float den = 0.f, acc = 0.f;
    for (int base = rs; base < re; base += 64) {
        int j = base + lane;
        if (j < re) {
            int s = csr[j];
            float e = __expf(lrelu(aS2[s] + adn));
            den += e;
            lds[wv][lane][0] = e;
            lds[wv][lane][1] = __int_as_float(s);
        }
        int cnt = min(64, re - base);
#pragma unroll 2
        for (int j2 = g; j2 < cnt; j2 += 4) {
            float2 es = *(const float2*)&lds[wv][j2][0];
            int s = __float_as_int(es.y);
            acc = fmaf(h2[s * OUT_F + fl], es.x, acc);
        }
    }
    den = wave_sum(den);
    acc += __shfl_xor(acc, 16);
    acc += __shfl_xor(acc, 32);
    float v = acc / den + bias2[fl];
    float mm = v;
#pragma unroll
    for (int o = 1; o < 16; o <<= 1) mm = fmaxf(mm, __shfl_xor(mm, o));
    float se = __expf(v - mm);
#pragma unroll
    for (int o = 1; o < 16; o <<= 1) se += __shfl_xor(se, o);
    float lse = mm + logf(se);
    if (lane < 16) out[n * OUT_F + fl] = v - lse;
}

extern "C" void kernel_launch(void* const* d_in, const int* in_sizes, int n_in,
                              void* d_out, int out_size, void* d_ws, size_t ws_size,
                              hipStream_t stream) {
    const float* x      = (const float*)d_in[0];
    const int*   ei     = (const int*)  d_in[1];
    const float* W1     = (const float*)d_in[2];
    const float* attS1  = (const float*)d_in[3];
    const float* attD1  = (const float*)d_in[4];
    const float* bias1  = (const float*)d_in[5];
    const float* W2     = (const float*)d_in[6];
    const float* attS2  = (const float*)d_in[7];
    const float* attD2  = (const float*)d_in[8];
    const float* bias2  = (const float*)d_in[9];
    const int* src = ei;
    const int* dst = ei + N_EDGES;
    float* out = (float*)d_out;
    (void)in_sizes; (void)n_in; (void)out_size; (void)ws_size;

    // ---- workspace layout ----
    char* wsb = (char*)d_ws;
    size_t off = 0;
    int* bcnt   = (int*)(wsb + off); off += 256 * 4;          // zero region
    size_t zero_bytes = off;
    int* boff   = (int*)(wsb + off); off += 257 * 4;
    int* bcur   = (int*)(wsb + off); off += 256 * 4;
    int* deg    = (int*)(wsb + off); off += (size_t)N_NODES * 4;
    int* inc    = (int*)(wsb + off); off += (size_t)N_NODES * 4;
    int* bsum   = (int*)(wsb + off); off += 256 * 4;
    int* row    = (int*)(wsb + off); off += ((size_t)N_NODES + 1) * 4;
    off = (off + 15) & ~(size_t)15;
    int* csr    = (int*)(wsb + off); off += (size_t)E_TOT * 4;
    off = (off + 15) & ~(size_t)15;
    bf16* h1    = (bf16*)(wsb + off); off += (size_t)N_NODES * C1 * 2;
    off = (off + 15) & ~(size_t)15;
    float* aS1p = (float*)(wsb + off); off += (size_t)N_NODES * 4 * 4;
    float* aD1p = (float*)(wsb + off); off += (size_t)N_NODES * 4 * 4;
    off = (off + 15) & ~(size_t)15;
    float* hmid = (float*)(wsb + off); off += (size_t)N_NODES * C1 * 4;
    float* h2   = (float*)(wsb + off); off += (size_t)N_NODES * OUT_F * 4;
    float* aS2  = (float*)(wsb + off); off += (size_t)N_NODES * 4;
    float* aD2  = (float*)(wsb + off); off += (size_t)N_NODES * 4;
    // bedge aliases hmid (13.2 MB <= 19.2 MB): used only before l1_node writes hmid
    int2* bedge = (int2*)hmid;

    hipMemsetAsync(d_ws, 0, zero_bytes, stream);

    // CSR build: bucketed counting sort
    k_bhist<<<NBLK_B, 256, 0, stream>>>(dst, bcnt);
    k_bscan<<<1, 256, 0, stream>>>(bcnt, boff, bcur);
    k_bucket<<<NBLK_B, 256, 0, stream>>>(src, dst, bcur, bedge);
    k_deg2<<<NBUCK, 256, 0, stream>>>(boff, bedge, deg);
    k_scan1<<<NB_SCAN, 256, 0, stream>>>(deg, inc, bsum);
    k_scan2<<<1, 256, 0, stream>>>(bsum);
    k_scan3<<<NB_SCAN, 256, 0, stream>>>(inc, bsum, row);
    k_scatter2<<<NBUCK, 256, 0, stream>>>(boff, bedge, row, csr);

    int nbn = N_NODES / 4;   // 12500, exact
    // layer 1
    int nbg = (N_NODES + BM - 1) / BM;   // 782
    l1_gemm<<<nbg, 256, 0, stream>>>(x, W1, attS1, attD1, h1, aS1p, aD1p);
    l1_node<<<nbn, 256, 0, stream>>>(row, csr, h1, aS1p, aD1p, bias1, hmid);
    // layer 2
    l2_mix<<<nbn, 256, 0, stream>>>(hmid, W2, attS2, attD2, h2, aS2, aD2);
    l2_node<<<nbn, 256, 0, stream>>>(row, csr, h2, aS2, aD2, bias2, out);
}

// Round 8
// 217.175 us; speedup vs baseline: 6.3036x; 1.0816x over previous
//
#include <hip/hip_runtime.h>
#include <hip/hip_bf16.h>

#define N_NODES 50000
#define N_EDGES 1600000
#define E_TOT   1650000   // edges + self loops
#define F_IN    128
#define HID     32
#define HEADS   3
#define C1      96        // HEADS*HID
#define OUT_F   16
#define NEG_SLOPE 0.2f
#define NB_SCAN 196       // ceil(50000/256)
#define BM      64        // l1_gemm node tile
#define NBUCK   196       // CSR coarse buckets: bucket = dst >> 8 (256 nodes each)
#define CHUNK   4096      // edges per block in bucket passes
#define NBLK_B  403       // ceil(E_TOT / CHUNK)

typedef __hip_bfloat16  bf16;
typedef __hip_bfloat162 bf162;

__device__ __forceinline__ float lrelu(float v) {
    return v > 0.f ? v : NEG_SLOPE * v;
}
__device__ __forceinline__ float wave_sum(float v) {
#pragma unroll
    for (int o = 32; o; o >>= 1) v += __shfl_xor(v, o);
    return v;
}

// ================= CSR construction: bucketed counting sort =================
// bedge entry: packed (src << 8) | (dst & 255); bucket id = dst >> 8.
__global__ __launch_bounds__(256) void k_bhist(const int* __restrict__ dst,
                                               int* __restrict__ bcnt) {
    __shared__ int h[NBUCK];
    for (int i = threadIdx.x; i < NBUCK; i += 256) h[i] = 0;
    __syncthreads();
    int base = blockIdx.x * CHUNK;
    int end = min(base + CHUNK, E_TOT);
    for (int e = base + threadIdx.x; e < end; e += 256) {
        int d = (e < N_EDGES) ? dst[e] : e - N_EDGES;
        atomicAdd(&h[d >> 8], 1);
    }
    __syncthreads();
    for (int i = threadIdx.x; i < NBUCK; i += 256)
        if (h[i]) atomicAdd(&bcnt[i], h[i]);
}

__global__ __launch_bounds__(256) void k_bscan(const int* __restrict__ bcnt,
                                               int* __restrict__ boff,
                                               int* __restrict__ bcur) {
    __shared__ int sh[256];
    int t = threadIdx.x;
    int v = (t < NBUCK) ? bcnt[t] : 0;
    sh[t] = v; __syncthreads();
#pragma unroll
    for (int o = 1; o < 256; o <<= 1) {
        int u = (t >= o) ? sh[t - o] : 0;
        __syncthreads();
        sh[t] += u;
        __syncthreads();
    }
    int ex = sh[t] - v;
    if (t < NBUCK) { boff[t] = ex; bcur[t] = ex; }
    if (t == NBUCK - 1) boff[NBUCK] = sh[t];
}

__global__ __launch_bounds__(256) void k_bucket(const int* __restrict__ src,
                                                const int* __restrict__ dst,
                                                int* __restrict__ bcur,
                                                int* __restrict__ bedge) {
    __shared__ int h[NBUCK], cur[NBUCK];
    for (int i = threadIdx.x; i < NBUCK; i += 256) h[i] = 0;
    __syncthreads();
    int base = blockIdx.x * CHUNK;
    int end = min(base + CHUNK, E_TOT);
    for (int e = base + threadIdx.x; e < end; e += 256) {
        int d = (e < N_EDGES) ? dst[e] : e - N_EDGES;
        atomicAdd(&h[d >> 8], 1);
    }
    __syncthreads();
    for (int i = threadIdx.x; i < NBUCK; i += 256)
        cur[i] = h[i] ? atomicAdd(&bcur[i], h[i]) : 0;
    __syncthreads();
    for (int e = base + threadIdx.x; e < end; e += 256) {
        int s, d;
        if (e < N_EDGES) { s = src[e]; d = dst[e]; }
        else { s = d = e - N_EDGES; }
        int slot = atomicAdd(&cur[d >> 8], 1);
        bedge[slot] = (s << 8) | (d & 255);
    }
}

__global__ __launch_bounds__(256) void k_deg2(const int* __restrict__ boff,
                                              const int* __restrict__ bedge,
                                              int* __restrict__ deg) {
    __shared__ int h[256];
    int b = blockIdx.x, t = threadIdx.x;
    h[t] = 0; __syncthreads();
    int s0 = boff[b], s1 = boff[b + 1];
    for (int i = s0 + t; i < s1; i += 256)
        atomicAdd(&h[bedge[i] & 255], 1);
    __syncthreads();
    int n = b * 256 + t;
    if (n < N_NODES) deg[n] = h[t];
}

__global__ void k_scan1(const int* __restrict__ deg, int* __restrict__ inc,
                        int* __restrict__ bsum) {
    __shared__ int sh[256];
    int t = threadIdx.x;
    int i = blockIdx.x * 256 + t;
    int v = (i < N_NODES) ? deg[i] : 0;
    sh[t] = v; __syncthreads();
#pragma unroll
    for (int o = 1; o < 256; o <<= 1) {
        int u = (t >= o) ? sh[t - o] : 0;
        __syncthreads();
        sh[t] += u;
        __syncthreads();
    }
    if (i < N_NODES) inc[i] = sh[t];
    if (t == 255) bsum[blockIdx.x] = sh[255];
}

__global__ void k_scan2(int* __restrict__ bsum) {
    __shared__ int sh[256];
    int t = threadIdx.x;
    int v = (t < NB_SCAN) ? bsum[t] : 0;
    sh[t] = v; __syncthreads();
#pragma unroll
    for (int o = 1; o < 256; o <<= 1) {
        int u = (t >= o) ? sh[t - o] : 0;
        __syncthreads();
        sh[t] += u;
        __syncthreads();
    }
    if (t < NB_SCAN) bsum[t] = sh[t];
}

__global__ void k_scan3(const int* __restrict__ inc, const int* __restrict__ bsum,
                        int* __restrict__ row) {
    int i = blockIdx.x * blockDim.x + threadIdx.x;
    if (i < N_NODES) {
        int add = blockIdx.x ? bsum[blockIdx.x - 1] : 0;
        row[i + 1] = inc[i] + add;
    }
    if (i == 0) row[0] = 0;
}

__global__ __launch_bounds__(256) void k_scatter2(const int* __restrict__ boff,
                                                  const int* __restrict__ bedge,
                                                  const int* __restrict__ row,
                                                  int* __restrict__ csr) {
    __shared__ int cur[256];
    int b = blockIdx.x, t = threadIdx.x;
    int n = b * 256 + t;
    cur[t] = (n < N_NODES) ? row[n] : 0;
    __syncthreads();
    int s0 = boff[b], s1 = boff[b + 1];
    for (int i = s0 + t; i < s1; i += 256) {
        int p = bedge[i];
        int slot = atomicAdd(&cur[p & 255], 1);
        csr[slot] = ((unsigned)p) >> 8;
    }
}

// ====== Layer 1 GEMM: register-tiled. Block = 64 nodes x 96 feats. h1 -> bf16 ======
__global__ __launch_bounds__(256) void l1_gemm(const float* __restrict__ x,
                                               const float* __restrict__ W1,
                                               const float* __restrict__ attS,
                                               const float* __restrict__ attD,
                                               bf16* __restrict__ h1,
                                               float* __restrict__ aS1p,
                                               float* __restrict__ aD1p) {
    __shared__ float xs[BM][F_IN + 4];   // stride 132: rows 4 banks apart
    int t = threadIdx.x;
    int tx = t & 15, ty = t >> 4;
    int n0 = blockIdx.x * BM;
    {
        const float4* xg = (const float4*)x;
#pragma unroll
        for (int it = 0; it < 8; ++it) {
            int idx = t + it * 256;
            int r = idx >> 5, c = idx & 31;
            int nn = n0 + r;
            float4 v = (nn < N_NODES) ? xg[nn * 32 + c]
                                      : make_float4(0.f, 0.f, 0.f, 0.f);
            *(float4*)&xs[r][c * 4] = v;
        }
    }
    __syncthreads();

    float acc[4][6];
#pragma unroll
    for (int i = 0; i < 4; ++i)
#pragma unroll
        for (int j = 0; j < 6; ++j) acc[i][j] = 0.f;

    int r0 = ty * 4;
    const float* wbase = W1 + tx;
#pragma unroll 4
    for (int k = 0; k < F_IN; k += 2) {
        float w0[6], w1[6];
#pragma unroll
        for (int j = 0; j < 6; ++j) {
            w0[j] = wbase[k * C1 + 16 * j];
            w1[j] = wbase[(k + 1) * C1 + 16 * j];
        }
        float2 xv[4];
#pragma unroll
        for (int i = 0; i < 4; ++i)
            xv[i] = *(const float2*)&xs[r0 + i][k];
#pragma unroll
        for (int i = 0; i < 4; ++i)
#pragma unroll
            for (int j = 0; j < 6; ++j) {
                acc[i][j] = fmaf(xv[i].x, w0[j], acc[i][j]);
                acc[i][j] = fmaf(xv[i].y, w1[j], acc[i][j]);
            }
    }

    float as[6], ad[6];
#pragma unroll
    for (int j = 0; j < 6; ++j) {
        as[j] = attS[tx + 16 * j];
        ad[j] = attD[tx + 16 * j];
    }
#pragma unroll
    for (int i = 0; i < 4; ++i) {
        int n = n0 + r0 + i;
        bool ok = (n < N_NODES);
        float ps0 = 0.f, ps1 = 0.f, ps2 = 0.f, pd0 = 0.f, pd1 = 0.f, pd2 = 0.f;
#pragma unroll
        for (int j = 0; j < 6; ++j) {
            if (ok) h1[n * C1 + tx + 16 * j] = __float2bfloat16(acc[i][j]);
            float vs = acc[i][j] * as[j], vd = acc[i][j] * ad[j];
            if (j < 2)      { ps0 += vs; pd0 += vd; }
            else if (j < 4) { ps1 += vs; pd1 += vd; }
            else            { ps2 += vs; pd2 += vd; }
        }
#pragma unroll
        for (int o = 1; o < 16; o <<= 1) {
            ps0 += __shfl_xor(ps0, o); pd0 += __shfl_xor(pd0, o);
            ps1 += __shfl_xor(ps1, o); pd1 += __shfl_xor(pd1, o);
            ps2 += __shfl_xor(ps2, o); pd2 += __shfl_xor(pd2, o);
        }
        if (ok && tx == 0) {
            aS1p[n * 4 + 0] = ps0; aS1p[n * 4 + 1] = ps1; aS1p[n * 4 + 2] = ps2;
            aS1p[n * 4 + 3] = 0.f;
            aD1p[n * 4 + 0] = pd0; aD1p[n * 4 + 1] = pd1; aD1p[n * 4 + 2] = pd2;
            aD1p[n * 4 + 3] = 0.f;
        }
    }
}

// ===== Layer 1 fused softmax+aggregate: 1 wave/node, bf16 gather, batch-8 MLP =====
__global__ __launch_bounds__(256) void l1_node(const int* __restrict__ row,
                                               const int* __restrict__ csr,
                                               const bf16* __restrict__ h1,
                                               const float* __restrict__ aS1p,
                                               const float* __restrict__ aD1p,
                                               const float* __restrict__ bias1,
                                               float* __restrict__ hout) {
    __shared__ float lds[4][3][65][2];   // [wave][head][entry(+pad)][{e, src}]
    int wv = threadIdx.x >> 6, lane = threadIdx.x & 63;
    int n = blockIdx.x * 4 + wv;
    int rs = row[n], re = row[n + 1];
    float4 adv = *(const float4*)&aD1p[n * 4];
    int f0 = (lane < 48) ? lane * 2 : 0;
    int hh = lane >> 4; if (hh > 2) hh = 2;
    float d0 = 0.f, d1 = 0.f, d2 = 0.f;
    float acc0 = 0.f, acc1 = 0.f;
    for (int base = rs; base < re; base += 64) {
        int j = base + lane;
        float e0 = 0.f, e1 = 0.f, e2 = 0.f;
        float sf = __int_as_float(0);
        if (j < re) {
            int s = csr[j];
            float4 a = *(const float4*)&aS1p[s * 4];
            e0 = __expf(lrelu(a.x + adv.x));
            e1 = __expf(lrelu(a.y + adv.y));
            e2 = __expf(lrelu(a.z + adv.z));
            sf = __int_as_float(s);
        }
        d0 += e0; d1 += e1; d2 += e2;
        lds[wv][0][lane][0] = e0; lds[wv][0][lane][1] = sf;
        lds[wv][1][lane][0] = e1; lds[wv][1][lane][1] = sf;
        lds[wv][2][lane][0] = e2; lds[wv][2][lane][1] = sf;
        int cnt8 = (min(64, re - base) + 7) & ~7;
        for (int j2 = 0; j2 < cnt8; j2 += 8) {
            float2 es[8];
#pragma unroll
            for (int u = 0; u < 8; ++u)
                es[u] = *(const float2*)&lds[wv][hh][j2 + u][0];
            float2 hv[8];
#pragma unroll
            for (int u = 0; u < 8; ++u) {
                int s = __float_as_int(es[u].y);
                hv[u] = __bfloat1622float2(*(const bf162*)&h1[s * C1 + f0]);
            }
#pragma unroll
            for (int u = 0; u < 8; ++u) {
                acc0 = fmaf(hv[u].x, es[u].x, acc0);
                acc1 = fmaf(hv[u].y, es[u].x, acc1);
            }
        }
    }
    d0 = wave_sum(d0); d1 = wave_sum(d1); d2 = wave_sum(d2);
    if (lane < 48) {
        float den = (hh == 0) ? d0 : (hh == 1) ? d1 : d2;
        float r = 1.f / den;
        float v0 = acc0 * r + bias1[f0];
        float v1 = acc1 * r + bias1[f0 + 1];
        float2 o;
        o.x = v0 > 0.f ? v0 : 0.f;
        o.y = v1 > 0.f ? v1 : 0.f;
        *(float2*)&hout[n * C1 + f0] = o;
    }
}

// ====== Layer 2 GEMM + att dots fused: 1 wave per node ======
__global__ __launch_bounds__(256) void l2_mix(const float* __restrict__ hmid,
                                              const float* __restrict__ W2,
                                              const float* __restrict__ attS,
                                              const float* __restrict__ attD,
                                              float* __restrict__ h2,
                                              float* __restrict__ aS2,
                                              float* __restrict__ aD2) {
    __shared__ float w[C1 * 17];         // W2 bank-padded [96][17]
    __shared__ float xs[4][100];         // hmid rows (pad 96->100)
    for (int i = threadIdx.x; i < C1 * OUT_F; i += 256)
        w[(i >> 4) * 17 + (i & 15)] = W2[i];
    __syncthreads();
    int wv = threadIdx.x >> 6, lane = threadIdx.x & 63;
    int n = blockIdx.x * 4 + wv;
    if (lane < 48)
        *(float2*)&xs[wv][lane * 2] = *(const float2*)&hmid[n * C1 + lane * 2];
    int g = lane >> 4, o = lane & 15;
    float acc = 0.f;
#pragma unroll 4
    for (int kk = 0; kk < 24; ++kk) {
        int k = g * 24 + kk;
        acc = fmaf(xs[wv][k], w[k * 17 + o], acc);
    }
    acc += __shfl_xor(acc, 16);
    acc += __shfl_xor(acc, 32);
    float ps = acc * attS[o];
    float pd = acc * attD[o];
#pragma unroll
    for (int s = 1; s < 16; s <<= 1) {
        ps += __shfl_xor(ps, s);
        pd += __shfl_xor(pd, s);
    }
    if (lane == 0) { aS2[n] = ps; aD2[n] = pd; }
    if (lane < 16) h2[n * OUT_F + o] = acc;
}

// ===== Layer 2 fused softmax+aggregate+bias+log_softmax: 1 wave/node, batch-8 =====
__global__ __launch_bounds__(256) void l2_node(const int* __restrict__ row,
                                               const int* __restrict__ csr,
                                               const float* __restrict__ h2,
                                               const float* __restrict__ aS2,
                                               const float* __restrict__ aD2,
                                               const float* __restrict__ bias2,
                                               float* __restrict__ out) {
    __shared__ float lds[4][64][2];      // [wave][entry][{e, src}]
    int wv = threadIdx.x >> 6, lane = threadIdx.x & 63;
    int n = blockIdx.x * 4 + wv;
    int rs = row[n], re = row[n + 1];
    float adn = aD2[n];
    int g = lane >> 4, fl = lane & 15;
    float den = 0.f, acc = 0.f;
    for (int base = rs; base < re; base += 64) {
        int j = base + lane;
        float e = 0.f;
        float sf = __int_as_float(0);
        if (j < re) {
            int s = csr[j];
            e = __expf(lrelu(aS2[s] + adn));
            sf = __int_as_float(s);
        }
        den += e;
        lds[wv][lane][0] = e;
        lds[wv][lane][1] = sf;
        int cnt = min(64, re - base);
        // group g owns contiguous quarter [g*16, g*16+16); batches of 8, skip if empty
#pragma unroll
        for (int b2 = 0; b2 < 2; ++b2) {
            int j0 = g * 16 + b2 * 8;
            if (j0 < cnt) {
                float2 es[8];
#pragma unroll
                for (int u = 0; u < 8; ++u)
                    es[u] = *(const float2*)&lds[wv][j0 + u][0];
                float hv[8];
#pragma unroll
                for (int u = 0; u < 8; ++u) {
                    int s = __float_as_int(es[u].y);
                    hv[u] = h2[s * OUT_F + fl];
                }
#pragma unroll
                for (int u = 0; u < 8; ++u)
                    acc = fmaf(hv[u], es[u].x, acc);
            }
        }
    }
    den = wave_sum(den);
    acc += __shfl_xor(acc, 16);
    acc += __shfl_xor(acc, 32);
    float v = acc / den + bias2[fl];
    float mm = v;
#pragma unroll
    for (int o = 1; o < 16; o <<= 1) mm = fmaxf(mm, __shfl_xor(mm, o));
    float se = __expf(v - mm);
#pragma unroll
    for (int o = 1; o < 16; o <<= 1) se += __shfl_xor(se, o);
    float lse = mm + logf(se);
    if (lane < 16) out[n * OUT_F + fl] = v - lse;
}

extern "C" void kernel_launch(void* const* d_in, const int* in_sizes, int n_in,
                              void* d_out, int out_size, void* d_ws, size_t ws_size,
                              hipStream_t stream) {
    const float* x      = (const float*)d_in[0];
    const int*   ei     = (const int*)  d_in[1];
    const float* W1     = (const float*)d_in[2];
    const float* attS1  = (const float*)d_in[3];
    const float* attD1  = (const float*)d_in[4];
    const float* bias1  = (const float*)d_in[5];
    const float* W2     = (const float*)d_in[6];
    const float* attS2  = (const float*)d_in[7];
    const float* attD2  = (const float*)d_in[8];
    const float* bias2  = (const float*)d_in[9];
    const int* src = ei;
    const int* dst = ei + N_EDGES;
    float* out = (float*)d_out;
    (void)in_sizes; (void)n_in; (void)out_size; (void)ws_size;

    // ---- workspace layout ----
    char* wsb = (char*)d_ws;
    size_t off = 0;
    int* bcnt   = (int*)(wsb + off); off += 256 * 4;          // zero region
    size_t zero_bytes = off;
    int* boff   = (int*)(wsb + off); off += 257 * 4;
    int* bcur   = (int*)(wsb + off); off += 256 * 4;
    int* deg    = (int*)(wsb + off); off += (size_t)N_NODES * 4;
    int* inc    = (int*)(wsb + off); off += (size_t)N_NODES * 4;
    int* bsum   = (int*)(wsb + off); off += 256 * 4;
    int* row    = (int*)(wsb + off); off += ((size_t)N_NODES + 1) * 4;
    off = (off + 15) & ~(size_t)15;
    int* csr    = (int*)(wsb + off); off += (size_t)E_TOT * 4;
    off = (off + 15) & ~(size_t)15;
    bf16* h1    = (bf16*)(wsb + off); off += (size_t)N_NODES * C1 * 2;
    off = (off + 15) & ~(size_t)15;
    float* aS1p = (float*)(wsb + off); off += (size_t)N_NODES * 4 * 4;
    float* aD1p = (float*)(wsb + off); off += (size_t)N_NODES * 4 * 4;
    off = (off + 15) & ~(size_t)15;
    float* hmid = (float*)(wsb + off); off += (size_t)N_NODES * C1 * 4;
    float* h2   = (float*)(wsb + off); off += (size_t)N_NODES * OUT_F * 4;
    float* aS2  = (float*)(wsb + off); off += (size_t)N_NODES * 4;
    float* aD2  = (float*)(wsb + off); off += (size_t)N_NODES * 4;
    // bedge aliases hmid (6.6 MB <= 19.2 MB): used only before l1_node writes hmid
    int* bedge = (int*)hmid;

    hipMemsetAsync(d_ws, 0, zero_bytes, stream);

    // CSR build: bucketed counting sort
    k_bhist<<<NBLK_B, 256, 0, stream>>>(dst, bcnt);
    k_bscan<<<1, 256, 0, stream>>>(bcnt, boff, bcur);
    k_bucket<<<NBLK_B, 256, 0, stream>>>(src, dst, bcur, bedge);
    k_deg2<<<NBUCK, 256, 0, stream>>>(boff, bedge, deg);
    k_scan1<<<NB_SCAN, 256, 0, stream>>>(deg, inc, bsum);
    k_scan2<<<1, 256, 0, stream>>>(bsum);
    k_scan3<<<NB_SCAN, 256, 0, stream>>>(inc, bsum, row);
    k_scatter2<<<NBUCK, 256, 0, stream>>>(boff, bedge, row, csr);

    int nbn = N_NODES / 4;   // 12500, exact
    // layer 1
    int nbg = (N_NODES + BM - 1) / BM;   // 782
    l1_gemm<<<nbg, 256, 0, stream>>>(x, W1, attS1, attD1, h1, aS1p, aD1p);
    l1_node<<<nbn, 256, 0, stream>>>(row, csr, h1, aS1p, aD1p, bias1, hmid);
    // layer 2
    l2_mix<<<nbn, 256, 0, stream>>>(hmid, W2, attS2, attD2, h2, aS2, aD2);
    l2_node<<<nbn, 256, 0, stream>>>(row, csr, h2, aS2, aD2, bias2, out);
}